// Round 13
// baseline (1725.475 us; speedup 1.0000x reference)
//
#include <hip/hip_runtime.h>
#include <hip/hip_bf16.h>

#define NN 100000
#define EE 1600000
#define RR 6
#define NBK 391        // dst/src buckets of 256 nodes
#define EB2 196        // edge blocks (8192 edges each)
#define CAP 4608       // per-bucket edge capacity (mean 4096, +8 sigma)

typedef __attribute__((ext_vector_type(8))) short bf16x8;
typedef __attribute__((ext_vector_type(4))) float f32x4;

__device__ inline short f2b(float x) {
    __hip_bfloat16 h = __float2bfloat16(x);
    return *reinterpret_cast<short*>(&h);
}
__device__ inline float b2f(short s) {
    __hip_bfloat16 h = *reinterpret_cast<__hip_bfloat16*>(&s);
    return __bfloat162float(h);
}
__device__ inline float ulo(unsigned u) { return __uint_as_float(u << 16); }
__device__ inline float uhi(unsigned u) { return __uint_as_float(u & 0xffff0000u); }
__device__ inline unsigned pck(float a, float b) {
    return (unsigned)(unsigned short)f2b(a) | ((unsigned)(unsigned short)f2b(b) << 16);
}

// ---------------- edge bucketing (fixed-capacity, no pre-count) ----------------

__global__ __launch_bounds__(256) void zero_cnts(int* p, int n) {
    int i = blockIdx.x * 256 + threadIdx.x;
    if (i < n) p[i] = 0;
}

__global__ __launch_bounds__(256) void bin_scatter(const int* __restrict__ src,
                                                   const int* __restrict__ dst,
                                                   int* __restrict__ bcurD,
                                                   int* __restrict__ bcurS,
                                                   unsigned* __restrict__ pairs,
                                                   unsigned char* __restrict__ srcs) {
    __shared__ int lcD[NBK], lbD[NBK], loD[NBK];
    __shared__ int lcS[NBK], lbS[NBK], loS[NBK];
    int t = threadIdx.x;
    for (int i = t; i < NBK; i += 256) { lcD[i] = 0; loD[i] = 0; lcS[i] = 0; loS[i] = 0; }
    __syncthreads();
    int base = blockIdx.x * 8192;
#pragma unroll
    for (int i = 0; i < 32; ++i) {
        int e = base + i * 256 + t;
        if (e < EE) {
            atomicAdd(&lcD[dst[e] >> 8], 1);
            atomicAdd(&lcS[src[e] >> 8], 1);
        }
    }
    __syncthreads();
    for (int i = t; i < NBK; i += 256) {
        lbD[i] = lcD[i] ? atomicAdd(&bcurD[i], lcD[i]) : 0;
        lbS[i] = lcS[i] ? atomicAdd(&bcurS[i], lcS[i]) : 0;
    }
    __syncthreads();
#pragma unroll
    for (int i = 0; i < 32; ++i) {
        int e = base + i * 256 + t;
        if (e < EE) {
            int s = src[e], d = dst[e];
            int bD = d >> 8, bS = s >> 8;
            int pD = lbD[bD] + atomicAdd(&loD[bD], 1);
            if (pD >= 0 && pD < CAP)
                pairs[(size_t)bD * CAP + pD] = ((unsigned)s << 8) | (unsigned)(d & 255);
            int pS = lbS[bS] + atomicAdd(&loS[bS], 1);
            if (pS >= 0 && pS < CAP)
                srcs[(size_t)bS * CAP + pS] = (unsigned char)(s & 255);
        }
    }
}

__global__ __launch_bounds__(512) void csr_build(const unsigned* __restrict__ pairs,
                                                 const int* __restrict__ bcurD,
                                                 int* __restrict__ rowp2,
                                                 int* __restrict__ csr) {
    __shared__ int hist[2048];
    __shared__ int wsums[4];
    int b = blockIdx.x, t = threadIdx.x;
    int p0 = b * CAP;
    int cnt = min(bcurD[b], CAP);
    int p1 = p0 + cnt;
    for (int i = t; i < 2048; i += 512) hist[i] = 0;
    __syncthreads();
    for (int e = p0 + t; e < p1; e += 512) {
        unsigned pr = pairs[e];
        int key = ((pr & 255) << 3) | (int)((pr >> 8) >> 14);
        atomicAdd(&hist[key], 1);
    }
    __syncthreads();
    int s[8] = {0, 0, 0, 0, 0, 0, 0, 0};
    int run = 0, x = 0;
    int lane = t & 63, wv = t >> 6;
    if (t < 256) {
#pragma unroll
        for (int i = 0; i < 8; ++i) { s[i] = run; run += hist[t * 8 + i]; }
        x = run;
#pragma unroll
        for (int d = 1; d < 64; d <<= 1) {
            int y = __shfl_up(x, d, 64);
            if (lane >= d) x += y;
        }
        if (lane == 63) wsums[wv] = x;
    }
    __syncthreads();
    if (t < 256) {
        int woff = 0;
        for (int wi = 0; wi < wv; ++wi) woff += wsums[wi];
        int excl = woff + x - run;
        rowp2[b * 257 + t] = p0 + excl;
        if (t == 0) rowp2[b * 257 + 256] = p1;
#pragma unroll
        for (int i = 0; i < 8; ++i) hist[t * 8 + i] = p0 + excl + s[i];   // absolute cursors
    }
    __syncthreads();
    for (int e = p0 + t; e < p1; e += 512) {
        unsigned pr = pairs[e];
        int key = ((pr & 255) << 3) | (int)((pr >> 8) >> 14);
        int pos = atomicAdd(&hist[key], 1);
        if (pos >= 0 && pos < NBK * CAP) csr[pos] = (int)(pr >> 8);
    }
}

__global__ __launch_bounds__(256) void deg_dis(const unsigned char* __restrict__ srcs,
                                               const int* __restrict__ bcurS,
                                               float* __restrict__ dis) {
    __shared__ int hist[256];
    int b = blockIdx.x, t = threadIdx.x;
    hist[t] = 0;
    __syncthreads();
    int cnt = min(bcurS[b], CAP);
    const unsigned char* sp = srcs + (size_t)b * CAP;
    for (int e = t; e < cnt; e += 256)
        atomicAdd(&hist[sp[e]], 1);
    __syncthreads();
    int node = b * 256 + t;
    if (node < NN) {
        int d = hist[t];
        dis[node] = d > 0 ? rsqrtf((float)d) : 0.f;
    }
}

// ---------------- x -> bf16 once ----------------
__global__ __launch_bounds__(256) void cvt_x(const float* __restrict__ x, short* __restrict__ xb) {
    int i = blockIdx.x * 256 + threadIdx.x;
    if (i >= NN * 128 / 8) return;
    const float* p = x + (size_t)i * 8;
    float4 u0 = *(const float4*)p;
    float4 u1 = *(const float4*)(p + 4);
    bf16x8 t;
    t[0] = f2b(u0.x); t[1] = f2b(u0.y); t[2] = f2b(u0.z); t[3] = f2b(u0.w);
    t[4] = f2b(u1.x); t[5] = f2b(u1.y); t[6] = f2b(u1.z); t[7] = f2b(u1.w);
    *(bf16x8*)(xb + (size_t)i * 8) = t;
}

// ---------------- weight packing into MFMA B-fragment order, hi/lo bf16 ----------------
__global__ __launch_bounds__(256) void wpack_cheb(const float* __restrict__ W, int Kin, int KS,
                                                  short* __restrict__ bh, short* __restrict__ bl) {
    int idx = blockIdx.x * 256 + threadIdx.x;
    int l = idx & 63;
    int q = idx >> 6;
    int s = q % KS; q /= KS;
    int t = q % 12; q /= 12;
    int r = q;
    if (r >= RR) return;
#pragma unroll
    for (int j = 0; j < 8; ++j) {
        int k = s * 32 + ((l >> 4) * 8) + j;
        int n = t * 16 + (l & 15);
        int g = n >> 6, jj = n & 63;
        float v = W[(((size_t)r * 3 + (g == 0 ? 0 : g)) * Kin + k) * 64 + jj];
        if (g == 0) v -= W[(((size_t)r * 3 + 2) * Kin + k) * 64 + jj];
        short hi = f2b(v);
        short lo = f2b(v - b2f(hi));
        bh[(size_t)idx * 8 + j] = hi;
        bl[(size_t)idx * 8 + j] = lo;
    }
}

__global__ __launch_bounds__(256) void wpack64(const float* __restrict__ W,
                                               short* __restrict__ bh, short* __restrict__ bl) {
    int idx = blockIdx.x * 256 + threadIdx.x;
    if (idx >= 512) return;
    int l = idx & 63;
    int s = (idx >> 6) & 1;
    int t = idx >> 7;
#pragma unroll
    for (int j = 0; j < 8; ++j) {
        int k = s * 32 + ((l >> 4) * 8) + j;
        int n = t * 16 + (l & 15);
        float v = W[k * 64 + n];
        short hi = f2b(v);
        short lo = f2b(v - b2f(hi));
        bh[(size_t)idx * 8 + j] = hi;
        bl[(size_t)idx * 8 + j] = lo;
    }
}

// ---------------- MFMA GEMM (A bf16, up to 3 bf16 outputs) ----------------
template <int KDIM>
__global__ __launch_bounds__(256) void gemm_mfma(const short* __restrict__ A, int lda,
                                                 const short* __restrict__ bph,
                                                 const short* __restrict__ bplo,
                                                 int nt0, int ntn, int s1, int s2,
                                                 short* __restrict__ o0, int ld0,
                                                 short* __restrict__ o1, int ld1,
                                                 short* __restrict__ o2, int ld2,
                                                 const float* __restrict__ bias,
                                                 int scale_from,
                                                 const float* __restrict__ rowscale,
                                                 int do_relu) {
    constexpr int KS = KDIM / 32;
    int w = threadIdx.x >> 6, l = threadIdx.x & 63;
    int rows0 = blockIdx.x * 64 + w * 16;
    int arow = rows0 + (l & 15);
    int kbase = (l >> 4) * 8;
    bf16x8 af[KS];
#pragma unroll
    for (int s = 0; s < KS; ++s) {
        bf16x8 t = {0, 0, 0, 0, 0, 0, 0, 0};
        if (arow < NN) t = *(const bf16x8*)(A + (size_t)arow * lda + s * 32 + kbase);
        af[s] = t;
    }
    for (int t = 0; t < ntn; ++t) {
        f32x4 acc = {0.f, 0.f, 0.f, 0.f};
        const short* bp0 = bph + (((size_t)(nt0 + t) * KS) * 64 + l) * 8;
        const short* bl0 = bplo + (((size_t)(nt0 + t) * KS) * 64 + l) * 8;
#pragma unroll
        for (int s = 0; s < KS; ++s) {
            bf16x8 bh = *(const bf16x8*)(bp0 + (size_t)s * 64 * 8);
            bf16x8 bl = *(const bf16x8*)(bl0 + (size_t)s * 64 * 8);
            acc = __builtin_amdgcn_mfma_f32_16x16x32_bf16(af[s], bh, acc, 0, 0, 0);
            acc = __builtin_amdgcn_mfma_f32_16x16x32_bf16(af[s], bl, acc, 0, 0, 0);
        }
        short* o;
        int ldc, tl;
        if (t < s1) { o = o0; ldc = ld0; tl = t; }
        else if (t < s2) { o = o1; ldc = ld1; tl = t - s1; }
        else { o = o2; ldc = ld2; tl = t - s2; }
        int lcol = (tl << 4) + (l & 15);
        bool scl = (rowscale != nullptr) && (t >= scale_from);
#pragma unroll
        for (int r_ = 0; r_ < 4; ++r_) {
            int row = rows0 + (l >> 4) * 4 + r_;
            if (row >= NN) continue;
            float v = acc[r_];
            if (bias) v += bias[lcol];
            if (do_relu) v = fmaxf(v, 0.f);
            if (scl) v *= rowscale[row];
            o[(size_t)row * ldc + lcol] = f2b(v);
        }
    }
}

// ---------------- SpMM: 8 lanes/row, 16B gathers, idx-prefetch pipeline ----------------
template <int MID>
__global__ __launch_bounds__(256) void spmm_bf(const short* __restrict__ v,
                                               const short* __restrict__ aux,
                                               short* __restrict__ outb, int ldc,
                                               const int* __restrict__ csr,
                                               const int* __restrict__ rowp2,
                                               const float* __restrict__ dis,
                                               const float* __restrict__ bias) {
    int t = threadIdx.x;
    int wv = t >> 6, l = t & 63;
    int g = l >> 3, fl = l & 7;               // 8-lane row-group, 8 feats/lane
    int row = blockIdx.x * 32 + wv * 8 + g;   // NN divisible by 32
    if (row >= NN) return;
    int b = row >> 8, ri = row & 255;
    int s0 = rowp2[b * 257 + ri];
    int s1 = rowp2[b * 257 + ri + 1];
    s0 = max(s0, b * CAP);
    s1 = min(s1, b * CAP + CAP);
    float a[8] = {0.f, 0.f, 0.f, 0.f, 0.f, 0.f, 0.f, 0.f};
    int e = s0;
    int idx[8], nidx[8];
    bool have = (e + 8 <= s1);
    if (have) {
#pragma unroll
        for (int i = 0; i < 8; ++i) idx[i] = csr[e + i];
    }
    while (have) {
        uint4 u[8];
#pragma unroll
        for (int i = 0; i < 8; ++i)
            u[i] = *(const uint4*)(v + (size_t)idx[i] * 64 + fl * 8);
        int en = e + 8;
        bool nhave = (en + 8 <= s1);
        if (nhave) {
#pragma unroll
            for (int i = 0; i < 8; ++i) nidx[i] = csr[en + i];
        }
#pragma unroll
        for (int i = 0; i < 8; ++i) {
            a[0] += ulo(u[i].x); a[1] += uhi(u[i].x);
            a[2] += ulo(u[i].y); a[3] += uhi(u[i].y);
            a[4] += ulo(u[i].z); a[5] += uhi(u[i].z);
            a[6] += ulo(u[i].w); a[7] += uhi(u[i].w);
        }
#pragma unroll
        for (int i = 0; i < 8; ++i) idx[i] = nidx[i];
        e = en;
        have = nhave;
    }
    for (; e < s1; ++e) {
        uint4 u = *(const uint4*)(v + (size_t)csr[e] * 64 + fl * 8);
        a[0] += ulo(u.x); a[1] += uhi(u.x);
        a[2] += ulo(u.y); a[3] += uhi(u.y);
        a[4] += ulo(u.z); a[5] += uhi(u.z);
        a[6] += ulo(u.w); a[7] += uhi(u.w);
    }
    float d = dis[row];
    uint4 au = *(const uint4*)(aux + (size_t)row * 64 + fl * 8);
    float av[8] = {ulo(au.x), uhi(au.x), ulo(au.y), uhi(au.y),
                   ulo(au.z), uhi(au.z), ulo(au.w), uhi(au.w)};
    float vv[8];
    if (MID) {
        float mm = -2.f * d * d;
#pragma unroll
        for (int i = 0; i < 8; ++i) vv[i] = av[i] + mm * a[i];
    } else {
        float4 bs0 = *(const float4*)(bias + fl * 8);
        float4 bs1 = *(const float4*)(bias + fl * 8 + 4);
        float bb[8] = {bs0.x, bs0.y, bs0.z, bs0.w, bs1.x, bs1.y, bs1.z, bs1.w};
#pragma unroll
        for (int i = 0; i < 8; ++i) vv[i] = fmaxf(av[i] - d * a[i] + bb[i], 0.f);
    }
    uint4 o;
    o.x = pck(vv[0], vv[1]); o.y = pck(vv[2], vv[3]);
    o.z = pck(vv[4], vv[5]); o.w = pck(vv[6], vv[7]);
    *(uint4*)(outb + (size_t)row * ldc + fl * 8) = o;
}

// ---------------- gate MLP + aux + softmax + fuse, one kernel ----------------
// block = 384 threads = 6 waves; each wave owns 4 A-tiles (64 (n,r) rows);
// block covers 64 whole nodes. glogit+softmax in LDS; fuse re-reads cache-hot stack.
__global__ __launch_bounds__(384) void gate_fuse(const short* __restrict__ stack,
                                                 const short* __restrict__ g1h,
                                                 const short* __restrict__ g1l,
                                                 const float* __restrict__ gb1,
                                                 const float* __restrict__ gw2,
                                                 const float* __restrict__ gb2,
                                                 const float* __restrict__ auxw,
                                                 const float* __restrict__ auxb,
                                                 short* __restrict__ hfused,
                                                 float* __restrict__ out) {
    __shared__ float glog[384];
    __shared__ float alpha[64][6];
    int t = threadIdx.x;
    int w = t / 64, l = t & 63;
    int nb = blockIdx.x * 64;
    int rowsw = nb * 6 + w * 64;
    int kbase = (l >> 4) * 8;
    bf16x8 af[4][2];
#pragma unroll
    for (int q = 0; q < 4; ++q) {
        int arow = rowsw + q * 16 + (l & 15);
        bool ok = arow < NN * RR;
#pragma unroll
        for (int s = 0; s < 2; ++s) {
            bf16x8 z = {0, 0, 0, 0, 0, 0, 0, 0};
            af[q][s] = ok ? *(const bf16x8*)(stack + (size_t)arow * 64 + s * 32 + kbase) : z;
        }
        int rmod = arow % RR;
        float paux = 0.f;
#pragma unroll
        for (int s = 0; s < 2; ++s) {
            const float* aw = auxw + rmod * 64 + s * 32 + kbase;
#pragma unroll
            for (int j = 0; j < 8; ++j) paux = fmaf(b2f(af[q][s][j]), aw[j], paux);
        }
        paux += __shfl_xor(paux, 16, 64);
        paux += __shfl_xor(paux, 32, 64);
        int orow = rowsw + q * 16 + l;
        if (l < 16 && orow < NN * RR) out[NN + (size_t)orow] = paux + auxb[orow % RR];
    }
    float pt[4][4];
#pragma unroll
    for (int q = 0; q < 4; ++q)
#pragma unroll
        for (int r_ = 0; r_ < 4; ++r_) pt[q][r_] = 0.f;
#pragma unroll
    for (int tc = 0; tc < 4; ++tc) {
        int col = tc * 16 + (l & 15);
        float bcol = gb1[col], w2 = gw2[col];
        bf16x8 bh0 = *(const bf16x8*)(g1h + (((size_t)tc * 2 + 0) * 64 + l) * 8);
        bf16x8 bl0 = *(const bf16x8*)(g1l + (((size_t)tc * 2 + 0) * 64 + l) * 8);
        bf16x8 bh1 = *(const bf16x8*)(g1h + (((size_t)tc * 2 + 1) * 64 + l) * 8);
        bf16x8 bl1 = *(const bf16x8*)(g1l + (((size_t)tc * 2 + 1) * 64 + l) * 8);
#pragma unroll
        for (int q = 0; q < 4; ++q) {
            f32x4 acc = {0.f, 0.f, 0.f, 0.f};
            acc = __builtin_amdgcn_mfma_f32_16x16x32_bf16(af[q][0], bh0, acc, 0, 0, 0);
            acc = __builtin_amdgcn_mfma_f32_16x16x32_bf16(af[q][0], bl0, acc, 0, 0, 0);
            acc = __builtin_amdgcn_mfma_f32_16x16x32_bf16(af[q][1], bh1, acc, 0, 0, 0);
            acc = __builtin_amdgcn_mfma_f32_16x16x32_bf16(af[q][1], bl1, acc, 0, 0, 0);
#pragma unroll
            for (int r_ = 0; r_ < 4; ++r_) {
                float h = fmaxf(acc[r_] + bcol, 0.f);
                pt[q][r_] = fmaf(h, w2, pt[q][r_]);
            }
        }
    }
#pragma unroll
    for (int q = 0; q < 4; ++q) {
#pragma unroll
        for (int d = 1; d < 16; d <<= 1)
#pragma unroll
            for (int r_ = 0; r_ < 4; ++r_) pt[q][r_] += __shfl_xor(pt[q][r_], d, 64);
        if ((l & 15) == 0) {
            float g2 = gb2[0];
#pragma unroll
            for (int r_ = 0; r_ < 4; ++r_)
                glog[w * 64 + q * 16 + (l >> 4) * 4 + r_] = pt[q][r_] + g2;
        }
    }
    __syncthreads();
    if (t < 64 && nb + t < NN) {
        float gl[RR];
        float m = -1e30f;
#pragma unroll
        for (int r = 0; r < RR; ++r) {
            gl[r] = glog[t * 6 + r];
            m = fmaxf(m, gl[r]);
        }
        float ssum = 0.f;
#pragma unroll
        for (int r = 0; r < RR; ++r) {
            gl[r] = __expf(gl[r] - m);
            ssum += gl[r];
        }
        float inv = 1.f / ssum;
#pragma unroll
        for (int r = 0; r < RR; ++r) alpha[t][r] = gl[r] * inv;
    }
    __syncthreads();
    for (int i = t; i < 2048; i += 384) {
        int nl = i >> 5, c2 = (i & 31) * 2;
        int n = nb + nl;
        if (n >= NN) break;
        float hf0 = 0.f, hf1 = 0.f;
#pragma unroll
        for (int r = 0; r < RR; ++r) {
            unsigned u = *(const unsigned*)(stack + ((size_t)n * RR + r) * 64 + c2);
            float al = alpha[nl][r];
            hf0 = fmaf(al, ulo(u), hf0);
            hf1 = fmaf(al, uhi(u), hf1);
        }
        *(unsigned*)(hfused + (size_t)n * 64 + c2) = pck(hf0, hf1);
    }
}

// ---------------- cls via MFMA ----------------
__global__ __launch_bounds__(256) void cls_mfma(const short* __restrict__ hproj,
                                                const short* __restrict__ c1h,
                                                const short* __restrict__ c1l,
                                                const float* __restrict__ cb1,
                                                const float* __restrict__ cw2,
                                                const float* __restrict__ cb2,
                                                float* __restrict__ out) {
    int w = threadIdx.x >> 6, l = threadIdx.x & 63;
    int rows0 = blockIdx.x * 64 + w * 16;
    int arow = rows0 + (l & 15);
    int kbase = (l >> 4) * 8;
    bf16x8 af[2];
#pragma unroll
    for (int s = 0; s < 2; ++s) {
        bf16x8 t = {0, 0, 0, 0, 0, 0, 0, 0};
        if (arow < NN) t = *(const bf16x8*)(hproj + (size_t)arow * 64 + s * 32 + kbase);
        af[s] = t;
    }
    float p[4] = {0.f, 0.f, 0.f, 0.f};
#pragma unroll
    for (int t = 0; t < 4; ++t) {
        f32x4 acc = {0.f, 0.f, 0.f, 0.f};
#pragma unroll
        for (int s = 0; s < 2; ++s) {
            bf16x8 bh = *(const bf16x8*)(c1h + (((size_t)t * 2 + s) * 64 + l) * 8);
            bf16x8 bl = *(const bf16x8*)(c1l + (((size_t)t * 2 + s) * 64 + l) * 8);
            acc = __builtin_amdgcn_mfma_f32_16x16x32_bf16(af[s], bh, acc, 0, 0, 0);
            acc = __builtin_amdgcn_mfma_f32_16x16x32_bf16(af[s], bl, acc, 0, 0, 0);
        }
        int col = t * 16 + (l & 15);
        float b = cb1[col], w2 = cw2[col];
#pragma unroll
        for (int r_ = 0; r_ < 4; ++r_) {
            float h = fmaxf(acc[r_] + b, 0.f);
            p[r_] = fmaf(h, w2, p[r_]);
        }
    }
#pragma unroll
    for (int d = 1; d < 16; d <<= 1) {
#pragma unroll
        for (int r_ = 0; r_ < 4; ++r_) p[r_] += __shfl_xor(p[r_], d, 64);
    }
    if ((l & 15) == 0) {
        float c2 = cb2[0];
#pragma unroll
        for (int r_ = 0; r_ < 4; ++r_) {
            int row = rows0 + (l >> 4) * 4 + r_;
            if (row < NN) out[row] = p[r_] + c2;
        }
    }
}

// ---------------- host ----------------

extern "C" void kernel_launch(void* const* d_in, const int* in_sizes, int n_in,
                              void* d_out, int out_size, void* d_ws, size_t ws_size,
                              hipStream_t stream) {
    const float* x = (const float*)d_in[0];
    const int* ei = (const int*)d_in[1];
    const float* c1w = (const float*)d_in[2];
    const float* c1b = (const float*)d_in[3];
    const float* c2w = (const float*)d_in[4];
    const float* c2b = (const float*)d_in[5];
    const float* gw1 = (const float*)d_in[6];
    const float* gb1 = (const float*)d_in[7];
    const float* gw2 = (const float*)d_in[8];
    const float* gb2 = (const float*)d_in[9];
    const float* pw = (const float*)d_in[10];
    const float* pb = (const float*)d_in[11];
    const float* cw1 = (const float*)d_in[12];
    const float* cb1 = (const float*)d_in[13];
    const float* cw2 = (const float*)d_in[14];
    const float* cb2 = (const float*)d_in[15];
    const float* auxw = (const float*)d_in[16];
    const float* auxb = (const float*)d_in[17];
    float* out = (float*)d_out;

    char* wsp = (char*)d_ws;
    size_t off = 0;
    auto carve = [&](size_t bytes) -> char* {
        char* p = wsp + off;
        off += (bytes + 255) & ~(size_t)255;
        return p;
    };
    short* stack = (short*)carve((size_t)NN * RR * 64 * 2);
    short* y1b = (short*)carve((size_t)NN * 64 * 2);          // aliases pairs
    short* y2b = (short*)carve((size_t)NN * 64 * 2);          // aliases srcs, hproj
    short* wb = (short*)carve((size_t)NN * 64 * 2);
    short* h1 = (short*)carve((size_t)NN * 64 * 2);           // also hfused
    short* t0b = (short*)carve((size_t)NN * 64 * 2);
    short* xb = (short*)carve((size_t)NN * 128 * 2);
    float* dis = (float*)carve((size_t)NN * 4);
    int* rowp2 = (int*)carve((size_t)NBK * 257 * 4);
    int* csr = (int*)carve((size_t)NBK * CAP * 4);
    int* cnts = (int*)carve((size_t)2 * RR * NBK * 4);
    short* bp1h = (short*)carve((size_t)RR * 12 * 4 * 64 * 8 * 2);
    short* bp1l = (short*)carve((size_t)RR * 12 * 4 * 64 * 8 * 2);
    short* bp2h = (short*)carve((size_t)RR * 12 * 2 * 64 * 8 * 2);
    short* bp2l = (short*)carve((size_t)RR * 12 * 2 * 64 * 8 * 2);
    short* g1h = (short*)carve((size_t)512 * 8 * 2);
    short* g1l = (short*)carve((size_t)512 * 8 * 2);
    short* pwh = (short*)carve((size_t)512 * 8 * 2);
    short* pwl = (short*)carve((size_t)512 * 8 * 2);
    short* c1h = (short*)carve((size_t)512 * 8 * 2);
    short* c1l = (short*)carve((size_t)512 * 8 * 2);
    unsigned* pairs = (unsigned*)y1b;
    unsigned char* srcs = (unsigned char*)y2b;
    short* hfused = h1;
    short* hproj = y2b;
    (void)in_sizes; (void)n_in; (void)out_size;

    if (off > ws_size) return;

    zero_cnts<<<(2 * RR * NBK + 255) / 256, 256, 0, stream>>>(cnts, 2 * RR * NBK);
    cvt_x<<<(NN * 128 / 8 + 255) / 256, 256, 0, stream>>>(x, xb);
    wpack_cheb<<<72, 256, 0, stream>>>(c1w, 128, 4, bp1h, bp1l);
    wpack_cheb<<<36, 256, 0, stream>>>(c2w, 64, 2, bp2h, bp2l);
    wpack64<<<2, 256, 0, stream>>>(gw1, g1h, g1l);
    wpack64<<<2, 256, 0, stream>>>(pw, pwh, pwl);
    wpack64<<<2, 256, 0, stream>>>(cw1, c1h, c1l);

    const int GB = 1563;
    for (int r = 0; r < RR; ++r) {
        const int* src = ei + (size_t)r * 2 * EE;
        const int* dst = src + EE;
        const short* b1h = bp1h + (size_t)r * 12 * 4 * 64 * 8;
        const short* b1l = bp1l + (size_t)r * 12 * 4 * 64 * 8;
        const short* b2h = bp2h + (size_t)r * 12 * 2 * 64 * 8;
        const short* b2l = bp2l + (size_t)r * 12 * 2 * 64 * 8;
        int* bcurD = cnts + (size_t)(2 * r + 0) * NBK;
        int* bcurS = cnts + (size_t)(2 * r + 1) * NBK;

        bin_scatter<<<EB2, 256, 0, stream>>>(src, dst, bcurD, bcurS, pairs, srcs);
        csr_build<<<NBK, 512, 0, stream>>>(pairs, bcurD, rowp2, csr);
        deg_dis<<<NBK, 256, 0, stream>>>(srcs, bcurS, dis);

        gemm_mfma<128><<<GB, 256, 0, stream>>>(xb, 128, b1h, b1l, 0, 12, 4, 8,
                                               t0b, 64, y1b, 64, y2b, 64,
                                               nullptr, 4, dis, 0);
        spmm_bf<1><<<NN / 32, 256, 0, stream>>>(y2b, y1b, wb, 64, csr, rowp2, dis, nullptr);
        spmm_bf<0><<<NN / 32, 256, 0, stream>>>(wb, t0b, h1, 64, csr, rowp2, dis,
                                                c1b + r * 64);
        gemm_mfma<64><<<GB, 256, 0, stream>>>(h1, 64, b2h, b2l, 0, 12, 4, 8,
                                              t0b, 64, y1b, 64, y2b, 64,
                                              nullptr, 4, dis, 0);
        spmm_bf<1><<<NN / 32, 256, 0, stream>>>(y2b, y1b, wb, 64, csr, rowp2, dis, nullptr);
        spmm_bf<0><<<NN / 32, 256, 0, stream>>>(wb, t0b, stack + r * 64, RR * 64,
                                                csr, rowp2, dis, c2b + r * 64);
    }
    gate_fuse<<<GB, 384, 0, stream>>>(stack, g1h, g1l, gb1, gw2, gb2,
                                      auxw, auxb, hfused, out);
    gemm_mfma<64><<<GB, 256, 0, stream>>>(hfused, 64, pwh, pwl, 0, 4, 4, 8,
                                          hproj, 64, nullptr, 0, nullptr, 0,
                                          pb, 99, nullptr, 1);
    cls_mfma<<<GB, 256, 0, stream>>>(hproj, c1h, c1l, cb1, cw2, cb2, out);
}

// Round 14
// 1586.910 us; speedup vs baseline: 1.0873x; 1.0873x over previous
//
#include <hip/hip_runtime.h>
#include <hip/hip_bf16.h>

#define NN 100000
#define EE 1600000
#define RR 6
#define NBK 391        // dst/src buckets of 256 nodes
#define EB2 196        // edge blocks (8192 edges each)
#define CAP 4608       // per-bucket edge capacity (mean 4096, +8 sigma)
#define GB 1563        // ceil(NN/64)

typedef __attribute__((ext_vector_type(8))) short bf16x8;
typedef __attribute__((ext_vector_type(4))) float f32x4;

__device__ inline short f2b(float x) {
    __hip_bfloat16 h = __float2bfloat16(x);
    return *reinterpret_cast<short*>(&h);
}
__device__ inline float b2f(short s) {
    __hip_bfloat16 h = *reinterpret_cast<__hip_bfloat16*>(&s);
    return __bfloat162float(h);
}
__device__ inline float ulo(unsigned u) { return __uint_as_float(u << 16); }
__device__ inline float uhi(unsigned u) { return __uint_as_float(u & 0xffff0000u); }
__device__ inline unsigned pck(float a, float b) {
    return (unsigned)(unsigned short)f2b(a) | ((unsigned)(unsigned short)f2b(b) << 16);
}

// ---------------- small setup kernels ----------------

__global__ __launch_bounds__(256) void zero_cnts(int* p, int n) {
    int i = blockIdx.x * 256 + threadIdx.x;
    if (i < n) p[i] = 0;
}

__global__ __launch_bounds__(256) void cvt_x(const float* __restrict__ x, short* __restrict__ xb) {
    int i = blockIdx.x * 256 + threadIdx.x;
    if (i >= NN * 128 / 8) return;
    const float* p = x + (size_t)i * 8;
    float4 u0 = *(const float4*)p;
    float4 u1 = *(const float4*)(p + 4);
    bf16x8 t;
    t[0] = f2b(u0.x); t[1] = f2b(u0.y); t[2] = f2b(u0.z); t[3] = f2b(u0.w);
    t[4] = f2b(u1.x); t[5] = f2b(u1.y); t[6] = f2b(u1.z); t[7] = f2b(u1.w);
    *(bf16x8*)(xb + (size_t)i * 8) = t;
}

__global__ __launch_bounds__(256) void wpack_cheb(const float* __restrict__ W, int Kin, int KS,
                                                  short* __restrict__ bh, short* __restrict__ bl) {
    int idx = blockIdx.x * 256 + threadIdx.x;
    int l = idx & 63;
    int q = idx >> 6;
    int s = q % KS; q /= KS;
    int t = q % 12; q /= 12;
    int r = q;
    if (r >= RR) return;
#pragma unroll
    for (int j = 0; j < 8; ++j) {
        int k = s * 32 + ((l >> 4) * 8) + j;
        int n = t * 16 + (l & 15);
        int g = n >> 6, jj = n & 63;
        float v = W[(((size_t)r * 3 + (g == 0 ? 0 : g)) * Kin + k) * 64 + jj];
        if (g == 0) v -= W[(((size_t)r * 3 + 2) * Kin + k) * 64 + jj];
        short hi = f2b(v);
        short lo = f2b(v - b2f(hi));
        bh[(size_t)idx * 8 + j] = hi;
        bl[(size_t)idx * 8 + j] = lo;
    }
}

__global__ __launch_bounds__(256) void wpack64(const float* __restrict__ W,
                                               short* __restrict__ bh, short* __restrict__ bl) {
    int idx = blockIdx.x * 256 + threadIdx.x;
    if (idx >= 512) return;
    int l = idx & 63;
    int s = (idx >> 6) & 1;
    int t = idx >> 7;
#pragma unroll
    for (int j = 0; j < 8; ++j) {
        int k = s * 32 + ((l >> 4) * 8) + j;
        int n = t * 16 + (l & 15);
        float v = W[k * 64 + n];
        short hi = f2b(v);
        short lo = f2b(v - b2f(hi));
        bh[(size_t)idx * 8 + j] = hi;
        bl[(size_t)idx * 8 + j] = lo;
    }
}

// ---------------- device bodies ----------------

// edge scatter into CAP-sized dst/src bucket regions (256 threads)
__device__ void dev_scatter(int bid, const int* __restrict__ src, const int* __restrict__ dst,
                            int* __restrict__ bcurD, int* __restrict__ bcurS,
                            unsigned* __restrict__ pairs, unsigned char* __restrict__ srcs) {
    __shared__ int lcD[NBK], lbD[NBK], loD[NBK];
    __shared__ int lcS[NBK], lbS[NBK], loS[NBK];
    int t = threadIdx.x;
    for (int i = t; i < NBK; i += 256) { lcD[i] = 0; loD[i] = 0; lcS[i] = 0; loS[i] = 0; }
    __syncthreads();
    int base = bid * 8192;
#pragma unroll
    for (int i = 0; i < 32; ++i) {
        int e = base + i * 256 + t;
        if (e < EE) {
            atomicAdd(&lcD[dst[e] >> 8], 1);
            atomicAdd(&lcS[src[e] >> 8], 1);
        }
    }
    __syncthreads();
    for (int i = t; i < NBK; i += 256) {
        lbD[i] = lcD[i] ? atomicAdd(&bcurD[i], lcD[i]) : 0;
        lbS[i] = lcS[i] ? atomicAdd(&bcurS[i], lcS[i]) : 0;
    }
    __syncthreads();
#pragma unroll
    for (int i = 0; i < 32; ++i) {
        int e = base + i * 256 + t;
        if (e < EE) {
            int s = src[e], d = dst[e];
            int bD = d >> 8, bS = s >> 8;
            int pD = lbD[bD] + atomicAdd(&loD[bD], 1);
            if (pD >= 0 && pD < CAP)
                pairs[(size_t)bD * CAP + pD] = ((unsigned)s << 8) | (unsigned)(d & 255);
            int pS = lbS[bS] + atomicAdd(&loS[bS], 1);
            if (pS >= 0 && pS < CAP)
                srcs[(size_t)bS * CAP + pS] = (unsigned char)(s & 255);
        }
    }
}

// per-dst-bucket CSR: key = dstLocal*8 | srcSlice; hist -> scan -> rowp2 -> scatter (256 thr)
__device__ void dev_csr(int b, const unsigned* __restrict__ pairs,
                        const int* __restrict__ bcurD,
                        int* __restrict__ rowp2, int* __restrict__ csr) {
    __shared__ int hist[2048];
    __shared__ int wsums[4];
    int t = threadIdx.x;
    int p0 = b * CAP;
    int cnt = min(bcurD[b], CAP);
    int p1 = p0 + cnt;
    for (int i = t; i < 2048; i += 256) hist[i] = 0;
    __syncthreads();
    for (int e = p0 + t; e < p1; e += 256) {
        unsigned pr = pairs[e];
        int key = ((pr & 255) << 3) | (int)((pr >> 8) >> 14);
        atomicAdd(&hist[key], 1);
    }
    __syncthreads();
    int s[8];
    int run = 0;
#pragma unroll
    for (int i = 0; i < 8; ++i) { s[i] = run; run += hist[t * 8 + i]; }
    int lane = t & 63, wv = t >> 6;
    int x = run;
#pragma unroll
    for (int d = 1; d < 64; d <<= 1) {
        int y = __shfl_up(x, d, 64);
        if (lane >= d) x += y;
    }
    if (lane == 63) wsums[wv] = x;
    __syncthreads();
    int woff = 0;
    for (int wi = 0; wi < wv; ++wi) woff += wsums[wi];
    int excl = woff + x - run;
    rowp2[b * 257 + t] = p0 + excl;
    if (t == 0) rowp2[b * 257 + 256] = p1;
    __syncthreads();
#pragma unroll
    for (int i = 0; i < 8; ++i) hist[t * 8 + i] = p0 + excl + s[i];
    __syncthreads();
    for (int e = p0 + t; e < p1; e += 256) {
        unsigned pr = pairs[e];
        int key = ((pr & 255) << 3) | (int)((pr >> 8) >> 14);
        int pos = atomicAdd(&hist[key], 1);
        if (pos >= 0 && pos < NBK * CAP) csr[pos] = (int)(pr >> 8);
    }
}

// per-src-bucket degree -> dis (256 threads)
__device__ void dev_deg(int b, const unsigned char* __restrict__ srcs,
                        const int* __restrict__ bcurS, float* __restrict__ dis) {
    __shared__ int hist2[256];
    int t = threadIdx.x;
    hist2[t] = 0;
    __syncthreads();
    int cnt = min(bcurS[b], CAP);
    const unsigned char* sp = srcs + (size_t)b * CAP;
    for (int e = t; e < cnt; e += 256)
        atomicAdd(&hist2[sp[e]], 1);
    __syncthreads();
    int node = b * 256 + t;
    if (node < NN) {
        int d = hist2[t];
        dis[node] = d > 0 ? rsqrtf((float)d) : 0.f;
    }
}

// MFMA GEMM tile body (256 threads). tiles t<s1 -> o0, t<s2 -> o1, else o2.
template <int KDIM>
__device__ void dev_gemm(int bid, const short* __restrict__ A, int lda,
                         const short* __restrict__ bph, const short* __restrict__ bplo,
                         int nt0, int ntn, int s1, int s2,
                         short* __restrict__ o0, int ld0,
                         short* __restrict__ o1, int ld1,
                         short* __restrict__ o2, int ld2,
                         const float* __restrict__ bias, int scale_from,
                         const float* __restrict__ rowscale, int do_relu) {
    constexpr int KS = KDIM / 32;
    int w = threadIdx.x >> 6, l = threadIdx.x & 63;
    int rows0 = bid * 64 + w * 16;
    int arow = rows0 + (l & 15);
    int kbase = (l >> 4) * 8;
    bf16x8 af[KS];
#pragma unroll
    for (int s = 0; s < KS; ++s) {
        bf16x8 t = {0, 0, 0, 0, 0, 0, 0, 0};
        if (arow < NN) t = *(const bf16x8*)(A + (size_t)arow * lda + s * 32 + kbase);
        af[s] = t;
    }
    for (int t = 0; t < ntn; ++t) {
        f32x4 acc = {0.f, 0.f, 0.f, 0.f};
        const short* bp0 = bph + (((size_t)(nt0 + t) * KS) * 64 + l) * 8;
        const short* bl0 = bplo + (((size_t)(nt0 + t) * KS) * 64 + l) * 8;
#pragma unroll
        for (int s = 0; s < KS; ++s) {
            bf16x8 bh = *(const bf16x8*)(bp0 + (size_t)s * 64 * 8);
            bf16x8 bl = *(const bf16x8*)(bl0 + (size_t)s * 64 * 8);
            acc = __builtin_amdgcn_mfma_f32_16x16x32_bf16(af[s], bh, acc, 0, 0, 0);
            acc = __builtin_amdgcn_mfma_f32_16x16x32_bf16(af[s], bl, acc, 0, 0, 0);
        }
        short* o;
        int ldc, tl;
        if (t < s1) { o = o0; ldc = ld0; tl = t; }
        else if (t < s2) { o = o1; ldc = ld1; tl = t - s1; }
        else { o = o2; ldc = ld2; tl = t - s2; }
        int lcol = (tl << 4) + (l & 15);
        bool scl = (rowscale != nullptr) && (t >= scale_from);
#pragma unroll
        for (int r_ = 0; r_ < 4; ++r_) {
            int row = rows0 + (l >> 4) * 4 + r_;
            if (row >= NN) continue;
            float v = acc[r_];
            if (bias) v += bias[lcol];
            if (do_relu) v = fmaxf(v, 0.f);
            if (scl) v *= rowscale[row];
            o[(size_t)row * ldc + lcol] = f2b(v);
        }
    }
}

// ---------------- standalone wrappers (prologue) ----------------

__global__ __launch_bounds__(256) void scatter_k(const int* src, const int* dst,
                                                 int* bcurD, int* bcurS,
                                                 unsigned* pairs, unsigned char* srcs) {
    dev_scatter(blockIdx.x, src, dst, bcurD, bcurS, pairs, srcs);
}

__global__ __launch_bounds__(256) void csrdeg_k(const unsigned* pairs, const unsigned char* srcs,
                                                const int* bcurD, const int* bcurS,
                                                int* rowp2, int* csr, float* dis) {
    int b = blockIdx.x;
    if (b < NBK) dev_csr(b, pairs, bcurD, rowp2, csr);
    else dev_deg(b - NBK, srcs, bcurS, dis);
}

// ---------------- fused launches: extra blocks FIRST for co-residency ----------------

template <int KDIM>
__global__ __launch_bounds__(256) void gemm_scatter(int nextra,
                                                    const short* A, int lda,
                                                    const short* bph, const short* bplo,
                                                    int nt0, int ntn, int s1, int s2,
                                                    short* o0, int ld0, short* o1, int ld1,
                                                    short* o2, int ld2,
                                                    const float* bias, int scale_from,
                                                    const float* rowscale, int do_relu,
                                                    const int* src, const int* dst,
                                                    int* bcurD, int* bcurS,
                                                    unsigned* pairs, unsigned char* srcs) {
    if ((int)blockIdx.x < nextra) {
        dev_scatter(blockIdx.x, src, dst, bcurD, bcurS, pairs, srcs);
    } else {
        dev_gemm<KDIM>(blockIdx.x - nextra, A, lda, bph, bplo, nt0, ntn, s1, s2,
                       o0, ld0, o1, ld1, o2, ld2, bias, scale_from, rowscale, do_relu);
    }
}

template <int KDIM>
__global__ __launch_bounds__(256) void gemm_csrdeg(int nextra,
                                                   const short* A, int lda,
                                                   const short* bph, const short* bplo,
                                                   int nt0, int ntn, int s1, int s2,
                                                   short* o0, int ld0, short* o1, int ld1,
                                                   short* o2, int ld2,
                                                   const float* bias, int scale_from,
                                                   const float* rowscale, int do_relu,
                                                   const unsigned* pairs, const unsigned char* srcs,
                                                   const int* bcurD, const int* bcurS,
                                                   int* rowp2n, int* csrn, float* disn) {
    if ((int)blockIdx.x < nextra) {
        int b = blockIdx.x;
        if (b < NBK) dev_csr(b, pairs, bcurD, rowp2n, csrn);
        else dev_deg(b - NBK, srcs, bcurS, disn);
    } else {
        dev_gemm<KDIM>(blockIdx.x - nextra, A, lda, bph, bplo, nt0, ntn, s1, s2,
                       o0, ld0, o1, ld1, o2, ld2, bias, scale_from, rowscale, do_relu);
    }
}

// ---------------- SpMM: 8 lanes/row, 16B gathers, idx-prefetch pipeline ----------------
// MID=1: outb[row,:] = bf16( aux[row,:] - 2*dis^2 * sum v[src,:] )           (aux=y1)
// MID=0: outb[row,:] = bf16( relu(aux[row,:] + (-dis)*sum v[src,:] + bias) )  (aux=t0; may be in-place)
template <int MID>
__global__ __launch_bounds__(256) void spmm_bf(const short* __restrict__ v,
                                               const short* __restrict__ aux,
                                               short* __restrict__ outb, int ldc,
                                               const int* __restrict__ csr,
                                               const int* __restrict__ rowp2,
                                               const float* __restrict__ dis,
                                               const float* __restrict__ bias) {
    int t = threadIdx.x;
    int wv = t >> 6, l = t & 63;
    int g = l >> 3, fl = l & 7;
    int row = blockIdx.x * 32 + wv * 8 + g;
    if (row >= NN) return;
    int b = row >> 8, ri = row & 255;
    int s0 = rowp2[b * 257 + ri];
    int s1 = rowp2[b * 257 + ri + 1];
    s0 = max(s0, b * CAP);
    s1 = min(s1, b * CAP + CAP);
    float a[8] = {0.f, 0.f, 0.f, 0.f, 0.f, 0.f, 0.f, 0.f};
    int e = s0;
    int idx[8], nidx[8];
    bool have = (e + 8 <= s1);
    if (have) {
#pragma unroll
        for (int i = 0; i < 8; ++i) idx[i] = csr[e + i];
    }
    while (have) {
        uint4 u[8];
#pragma unroll
        for (int i = 0; i < 8; ++i)
            u[i] = *(const uint4*)(v + (size_t)idx[i] * 64 + fl * 8);
        int en = e + 8;
        bool nhave = (en + 8 <= s1);
        if (nhave) {
#pragma unroll
            for (int i = 0; i < 8; ++i) nidx[i] = csr[en + i];
        }
#pragma unroll
        for (int i = 0; i < 8; ++i) {
            a[0] += ulo(u[i].x); a[1] += uhi(u[i].x);
            a[2] += ulo(u[i].y); a[3] += uhi(u[i].y);
            a[4] += ulo(u[i].z); a[5] += uhi(u[i].z);
            a[6] += ulo(u[i].w); a[7] += uhi(u[i].w);
        }
#pragma unroll
        for (int i = 0; i < 8; ++i) idx[i] = nidx[i];
        e = en;
        have = nhave;
    }
    for (; e < s1; ++e) {
        uint4 u = *(const uint4*)(v + (size_t)csr[e] * 64 + fl * 8);
        a[0] += ulo(u.x); a[1] += uhi(u.x);
        a[2] += ulo(u.y); a[3] += uhi(u.y);
        a[4] += ulo(u.z); a[5] += uhi(u.z);
        a[6] += ulo(u.w); a[7] += uhi(u.w);
    }
    float d = dis[row];
    uint4 au = *(const uint4*)(aux + (size_t)row * 64 + fl * 8);
    float av[8] = {ulo(au.x), uhi(au.x), ulo(au.y), uhi(au.y),
                   ulo(au.z), uhi(au.z), ulo(au.w), uhi(au.w)};
    float vv[8];
    if (MID) {
        float mm = -2.f * d * d;
#pragma unroll
        for (int i = 0; i < 8; ++i) vv[i] = av[i] + mm * a[i];
    } else {
        float4 bs0 = *(const float4*)(bias + fl * 8);
        float4 bs1 = *(const float4*)(bias + fl * 8 + 4);
        float bb[8] = {bs0.x, bs0.y, bs0.z, bs0.w, bs1.x, bs1.y, bs1.z, bs1.w};
#pragma unroll
        for (int i = 0; i < 8; ++i) vv[i] = fmaxf(av[i] - d * a[i] + bb[i], 0.f);
    }
    uint4 o;
    o.x = pck(vv[0], vv[1]); o.y = pck(vv[2], vv[3]);
    o.z = pck(vv[4], vv[5]); o.w = pck(vv[6], vv[7]);
    *(uint4*)(outb + (size_t)row * ldc + fl * 8) = o;
}

// ---------------- gate MLP + aux + softmax + fuse ----------------
__global__ __launch_bounds__(384) void gate_fuse(const short* __restrict__ stack,
                                                 const short* __restrict__ g1h,
                                                 const short* __restrict__ g1l,
                                                 const float* __restrict__ gb1,
                                                 const float* __restrict__ gw2,
                                                 const float* __restrict__ gb2,
                                                 const float* __restrict__ auxw,
                                                 const float* __restrict__ auxb,
                                                 short* __restrict__ hfused,
                                                 float* __restrict__ out) {
    __shared__ float glog[384];
    __shared__ float alpha[64][6];
    int t = threadIdx.x;
    int w = t / 64, l = t & 63;
    int nb = blockIdx.x * 64;
    int rowsw = nb * 6 + w * 64;
    int kbase = (l >> 4) * 8;
    bf16x8 af[4][2];
#pragma unroll
    for (int q = 0; q < 4; ++q) {
        int arow = rowsw + q * 16 + (l & 15);
        bool ok = arow < NN * RR;
#pragma unroll
        for (int s = 0; s < 2; ++s) {
            bf16x8 z = {0, 0, 0, 0, 0, 0, 0, 0};
            af[q][s] = ok ? *(const bf16x8*)(stack + (size_t)arow * 64 + s * 32 + kbase) : z;
        }
        int rmod = arow % RR;
        float paux = 0.f;
#pragma unroll
        for (int s = 0; s < 2; ++s) {
            const float* aw = auxw + rmod * 64 + s * 32 + kbase;
#pragma unroll
            for (int j = 0; j < 8; ++j) paux = fmaf(b2f(af[q][s][j]), aw[j], paux);
        }
        paux += __shfl_xor(paux, 16, 64);
        paux += __shfl_xor(paux, 32, 64);
        int orow = rowsw + q * 16 + l;
        if (l < 16 && orow < NN * RR) out[NN + (size_t)orow] = paux + auxb[orow % RR];
    }
    float pt[4][4];
#pragma unroll
    for (int q = 0; q < 4; ++q)
#pragma unroll
        for (int r_ = 0; r_ < 4; ++r_) pt[q][r_] = 0.f;
#pragma unroll
    for (int tc = 0; tc < 4; ++tc) {
        int col = tc * 16 + (l & 15);
        float bcol = gb1[col], w2 = gw2[col];
        bf16x8 bh0 = *(const bf16x8*)(g1h + (((size_t)tc * 2 + 0) * 64 + l) * 8);
        bf16x8 bl0 = *(const bf16x8*)(g1l + (((size_t)tc * 2 + 0) * 64 + l) * 8);
        bf16x8 bh1 = *(const bf16x8*)(g1h + (((size_t)tc * 2 + 1) * 64 + l) * 8);
        bf16x8 bl1 = *(const bf16x8*)(g1l + (((size_t)tc * 2 + 1) * 64 + l) * 8);
#pragma unroll
        for (int q = 0; q < 4; ++q) {
            f32x4 acc = {0.f, 0.f, 0.f, 0.f};
            acc = __builtin_amdgcn_mfma_f32_16x16x32_bf16(af[q][0], bh0, acc, 0, 0, 0);
            acc = __builtin_amdgcn_mfma_f32_16x16x32_bf16(af[q][0], bl0, acc, 0, 0, 0);
            acc = __builtin_amdgcn_mfma_f32_16x16x32_bf16(af[q][1], bh1, acc, 0, 0, 0);
            acc = __builtin_amdgcn_mfma_f32_16x16x32_bf16(af[q][1], bl1, acc, 0, 0, 0);
#pragma unroll
            for (int r_ = 0; r_ < 4; ++r_) {
                float h = fmaxf(acc[r_] + bcol, 0.f);
                pt[q][r_] = fmaf(h, w2, pt[q][r_]);
            }
        }
    }
#pragma unroll
    for (int q = 0; q < 4; ++q) {
#pragma unroll
        for (int d = 1; d < 16; d <<= 1)
#pragma unroll
            for (int r_ = 0; r_ < 4; ++r_) pt[q][r_] += __shfl_xor(pt[q][r_], d, 64);
        if ((l & 15) == 0) {
            float g2 = gb2[0];
#pragma unroll
            for (int r_ = 0; r_ < 4; ++r_)
                glog[w * 64 + q * 16 + (l >> 4) * 4 + r_] = pt[q][r_] + g2;
        }
    }
    __syncthreads();
    if (t < 64 && nb + t < NN) {
        float gl[RR];
        float m = -1e30f;
#pragma unroll
        for (int r = 0; r < RR; ++r) {
            gl[r] = glog[t * 6 + r];
            m = fmaxf(m, gl[r]);
        }
        float ssum = 0.f;
#pragma unroll
        for (int r = 0; r < RR; ++r) {
            gl[r] = __expf(gl[r] - m);
            ssum += gl[r];
        }
        float inv = 1.f / ssum;
#pragma unroll
        for (int r = 0; r < RR; ++r) alpha[t][r] = gl[r] * inv;
    }
    __syncthreads();
    for (int i = t; i < 2048; i += 384) {
        int nl = i >> 5, c2 = (i & 31) * 2;
        int n = nb + nl;
        if (n >= NN) break;
        float hf0 = 0.f, hf1 = 0.f;
#pragma unroll
        for (int r = 0; r < RR; ++r) {
            unsigned u = *(const unsigned*)(stack + ((size_t)n * RR + r) * 64 + c2);
            float al = alpha[nl][r];
            hf0 = fmaf(al, ulo(u), hf0);
            hf1 = fmaf(al, uhi(u), hf1);
        }
        *(unsigned*)(hfused + (size_t)n * 64 + c2) = pck(hf0, hf1);
    }
}

// ---------------- cls via MFMA ----------------
__global__ __launch_bounds__(256) void cls_mfma(const short* __restrict__ hproj,
                                                const short* __restrict__ c1h,
                                                const short* __restrict__ c1l,
                                                const float* __restrict__ cb1,
                                                const float* __restrict__ cw2,
                                                const float* __restrict__ cb2,
                                                float* __restrict__ out) {
    int w = threadIdx.x >> 6, l = threadIdx.x & 63;
    int rows0 = blockIdx.x * 64 + w * 16;
    int arow = rows0 + (l & 15);
    int kbase = (l >> 4) * 8;
    bf16x8 af[2];
#pragma unroll
    for (int s = 0; s < 2; ++s) {
        bf16x8 t = {0, 0, 0, 0, 0, 0, 0, 0};
        if (arow < NN) t = *(const bf16x8*)(hproj + (size_t)arow * 64 + s * 32 + kbase);
        af[s] = t;
    }
    float p[4] = {0.f, 0.f, 0.f, 0.f};
#pragma unroll
    for (int t = 0; t < 4; ++t) {
        f32x4 acc = {0.f, 0.f, 0.f, 0.f};
#pragma unroll
        for (int s = 0; s < 2; ++s) {
            bf16x8 bh = *(const bf16x8*)(c1h + (((size_t)t * 2 + s) * 64 + l) * 8);
            bf16x8 bl = *(const bf16x8*)(c1l + (((size_t)t * 2 + s) * 64 + l) * 8);
            acc = __builtin_amdgcn_mfma_f32_16x16x32_bf16(af[s], bh, acc, 0, 0, 0);
            acc = __builtin_amdgcn_mfma_f32_16x16x32_bf16(af[s], bl, acc, 0, 0, 0);
        }
        int col = t * 16 + (l & 15);
        float b = cb1[col], w2 = cw2[col];
#pragma unroll
        for (int r_ = 0; r_ < 4; ++r_) {
            float h = fmaxf(acc[r_] + b, 0.f);
            p[r_] = fmaf(h, w2, p[r_]);
        }
    }
#pragma unroll
    for (int d = 1; d < 16; d <<= 1) {
#pragma unroll
        for (int r_ = 0; r_ < 4; ++r_) p[r_] += __shfl_xor(p[r_], d, 64);
    }
    if ((l & 15) == 0) {
        float c2 = cb2[0];
#pragma unroll
        for (int r_ = 0; r_ < 4; ++r_) {
            int row = rows0 + (l >> 4) * 4 + r_;
            if (row < NN) out[row] = p[r_] + c2;
        }
    }
}

// ---------------- host ----------------

extern "C" void kernel_launch(void* const* d_in, const int* in_sizes, int n_in,
                              void* d_out, int out_size, void* d_ws, size_t ws_size,
                              hipStream_t stream) {
    const float* x = (const float*)d_in[0];
    const int* ei = (const int*)d_in[1];
    const float* c1w = (const float*)d_in[2];
    const float* c1b = (const float*)d_in[3];
    const float* c2w = (const float*)d_in[4];
    const float* c2b = (const float*)d_in[5];
    const float* gw1 = (const float*)d_in[6];
    const float* gb1 = (const float*)d_in[7];
    const float* gw2 = (const float*)d_in[8];
    const float* gb2 = (const float*)d_in[9];
    const float* pw = (const float*)d_in[10];
    const float* pb = (const float*)d_in[11];
    const float* cw1 = (const float*)d_in[12];
    const float* cb1 = (const float*)d_in[13];
    const float* cw2 = (const float*)d_in[14];
    const float* cb2 = (const float*)d_in[15];
    const float* auxw = (const float*)d_in[16];
    const float* auxb = (const float*)d_in[17];
    float* out = (float*)d_out;

    char* wsp = (char*)d_ws;
    size_t off = 0;
    auto carve = [&](size_t bytes) -> char* {
        char* p = wsp + off;
        off += (bytes + 255) & ~(size_t)255;
        return p;
    };
    short* stack = (short*)carve((size_t)NN * RR * 64 * 2);
    short* y1b = (short*)carve((size_t)NN * 64 * 2);
    short* y2b = (short*)carve((size_t)NN * 64 * 2);          // also hproj
    short* wb = (short*)carve((size_t)NN * 64 * 2);
    short* tb = (short*)carve((size_t)NN * 64 * 2);           // t0 / h1 (in-place) / hfused
    short* xb = (short*)carve((size_t)NN * 128 * 2);
    float* dis = (float*)carve((size_t)2 * NN * 4);           // double-buffered
    int* rowp2 = (int*)carve((size_t)2 * NBK * 257 * 4);      // double-buffered
    int* csr = (int*)carve((size_t)2 * NBK * CAP * 4);        // double-buffered
    unsigned* pairs = (unsigned*)carve((size_t)NBK * CAP * 4);   // dedicated
    unsigned char* srcs = (unsigned char*)carve((size_t)NBK * CAP);  // dedicated
    int* cnts = (int*)carve((size_t)2 * RR * NBK * 4);
    short* bp1h = (short*)carve((size_t)RR * 12 * 4 * 64 * 8 * 2);
    short* bp1l = (short*)carve((size_t)RR * 12 * 4 * 64 * 8 * 2);
    short* bp2h = (short*)carve((size_t)RR * 12 * 2 * 64 * 8 * 2);
    short* bp2l = (short*)carve((size_t)RR * 12 * 2 * 64 * 8 * 2);
    short* g1h = (short*)carve((size_t)512 * 8 * 2);
    short* g1l = (short*)carve((size_t)512 * 8 * 2);
    short* pwh = (short*)carve((size_t)512 * 8 * 2);
    short* pwl = (short*)carve((size_t)512 * 8 * 2);
    short* c1h = (short*)carve((size_t)512 * 8 * 2);
    short* c1l = (short*)carve((size_t)512 * 8 * 2);
    (void)in_sizes; (void)n_in; (void)out_size;

    if (off > ws_size) return;   // guard: clean absmax-fail => ws too small

    zero_cnts<<<(2 * RR * NBK + 255) / 256, 256, 0, stream>>>(cnts, 2 * RR * NBK);
    cvt_x<<<(NN * 128 / 8 + 255) / 256, 256, 0, stream>>>(x, xb);
    wpack_cheb<<<72, 256, 0, stream>>>(c1w, 128, 4, bp1h, bp1l);
    wpack_cheb<<<36, 256, 0, stream>>>(c2w, 64, 2, bp2h, bp2l);
    wpack64<<<2, 256, 0, stream>>>(gw1, g1h, g1l);
    wpack64<<<2, 256, 0, stream>>>(pw, pwh, pwl);
    wpack64<<<2, 256, 0, stream>>>(cw1, c1h, c1l);

    // prologue: build CSR for relation 0
    scatter_k<<<EB2, 256, 0, stream>>>(ei, ei + EE, cnts, cnts + NBK, pairs, srcs);
    csrdeg_k<<<2 * NBK, 256, 0, stream>>>(pairs, srcs, cnts, cnts + NBK,
                                          rowp2, csr, dis);

    for (int r = 0; r < RR; ++r) {
        int cur = r & 1, nxt = cur ^ 1;
        int valid = (r < RR - 1) ? 1 : 0;
        const short* b1h = bp1h + (size_t)r * 12 * 4 * 64 * 8;
        const short* b1l = bp1l + (size_t)r * 12 * 4 * 64 * 8;
        const short* b2h = bp2h + (size_t)r * 12 * 2 * 64 * 8;
        const short* b2l = bp2l + (size_t)r * 12 * 2 * 64 * 8;
        const int* srcN = ei + (size_t)(r + 1) * 2 * EE;   // only deref'd when valid
        const int* dstN = srcN + EE;
        int* bcurDN = cnts + (size_t)(2 * (r + 1) % (2 * RR)) * NBK;
        int* bcurSN = bcurDN + NBK;
        const int* csrC = csr + (size_t)cur * NBK * CAP;
        const int* rowp2C = rowp2 + (size_t)cur * NBK * 257;
        const float* disC = dis + (size_t)cur * NN;
        int* csrN = csr + (size_t)nxt * NBK * CAP;
        int* rowp2N = rowp2 + (size_t)nxt * NBK * 257;
        float* disN = dis + (size_t)nxt * NN;

        // layer 1 GEMM + (scatter for r+1)
        gemm_scatter<128><<<GB + (valid ? EB2 : 0), 256, 0, stream>>>(
            valid ? EB2 : 0, xb, 128, b1h, b1l, 0, 12, 4, 8,
            tb, 64, y1b, 64, y2b, 64, nullptr, 4, disC, 0,
            srcN, dstN, bcurDN, bcurSN, pairs, srcs);
        spmm_bf<1><<<NN / 32, 256, 0, stream>>>(y2b, y1b, wb, 64, csrC, rowp2C, disC, nullptr);
        spmm_bf<0><<<NN / 32, 256, 0, stream>>>(wb, tb, tb, 64, csrC, rowp2C, disC,
                                                c1b + r * 64);   // h1 in-place in tb
        // layer 2 GEMM + (csr_build + deg_dis for r+1)
        gemm_csrdeg<64><<<GB + (valid ? 2 * NBK : 0), 256, 0, stream>>>(
            valid ? 2 * NBK : 0, tb, 64, b2h, b2l, 0, 12, 4, 8,
            tb, 64, y1b, 64, y2b, 64, nullptr, 4, disC, 0,
            pairs, srcs, bcurDN, bcurSN, rowp2N, csrN, disN);
        spmm_bf<1><<<NN / 32, 256, 0, stream>>>(y2b, y1b, wb, 64, csrC, rowp2C, disC, nullptr);
        spmm_bf<0><<<NN / 32, 256, 0, stream>>>(wb, tb, stack + r * 64, RR * 64,
                                                csrC, rowp2C, disC, c2b + r * 64);
    }
    gate_fuse<<<GB, 384, 0, stream>>>(stack, g1h, g1l, gb1, gw2, gb2,
                                      auxw, auxb, tb, out);
    gemm_scatter<64><<<GB, 256, 0, stream>>>(0, tb, 64, pwh, pwl, 0, 4, 4, 8,
                                             y2b, 64, nullptr, 0, nullptr, 0,
                                             pb, 99, nullptr, 1,
                                             nullptr, nullptr, nullptr, nullptr,
                                             nullptr, nullptr);
    cls_mfma<<<GB, 256, 0, stream>>>(y2b, c1h, c1l, cb1, cw2, cb2, out);
}

// Round 15
// 1404.355 us; speedup vs baseline: 1.2287x; 1.1300x over previous
//
#include <hip/hip_runtime.h>
#include <hip/hip_bf16.h>

#define NN 100000
#define EE 1600000
#define RR 6
#define NBK 391        // dst/src buckets of 256 nodes
#define EB2 196        // edge blocks (8192 edges each)
#define CAP 4608       // per-bucket edge capacity (mean 4096, +8 sigma)
#define GB 1563        // ceil(NN/64)

typedef __attribute__((ext_vector_type(8))) short bf16x8;
typedef __attribute__((ext_vector_type(4))) float f32x4;

__device__ inline short f2b(float x) {
    __hip_bfloat16 h = __float2bfloat16(x);
    return *reinterpret_cast<short*>(&h);
}
__device__ inline float b2f(short s) {
    __hip_bfloat16 h = *reinterpret_cast<__hip_bfloat16*>(&s);
    return __bfloat162float(h);
}
__device__ inline float ulo(unsigned u) { return __uint_as_float(u << 16); }
__device__ inline float uhi(unsigned u) { return __uint_as_float(u & 0xffff0000u); }
__device__ inline unsigned pck(float a, float b) {
    return (unsigned)(unsigned short)f2b(a) | ((unsigned)(unsigned short)f2b(b) << 16);
}

// ---------------- small setup kernels ----------------

__global__ __launch_bounds__(256) void zero_cnts(int* p, int n) {
    int i = blockIdx.x * 256 + threadIdx.x;
    if (i < n) p[i] = 0;
}

__global__ __launch_bounds__(256) void cvt_x(const float* __restrict__ x, short* __restrict__ xb) {
    int i = blockIdx.x * 256 + threadIdx.x;
    if (i >= NN * 128 / 8) return;
    const float* p = x + (size_t)i * 8;
    float4 u0 = *(const float4*)p;
    float4 u1 = *(const float4*)(p + 4);
    bf16x8 t;
    t[0] = f2b(u0.x); t[1] = f2b(u0.y); t[2] = f2b(u0.z); t[3] = f2b(u0.w);
    t[4] = f2b(u1.x); t[5] = f2b(u1.y); t[6] = f2b(u1.z); t[7] = f2b(u1.w);
    *(bf16x8*)(xb + (size_t)i * 8) = t;
}

__global__ __launch_bounds__(256) void wpack_cheb(const float* __restrict__ W, int Kin, int KS,
                                                  short* __restrict__ bh, short* __restrict__ bl) {
    int idx = blockIdx.x * 256 + threadIdx.x;
    int l = idx & 63;
    int q = idx >> 6;
    int s = q % KS; q /= KS;
    int t = q % 12; q /= 12;
    int r = q;
    if (r >= RR) return;
#pragma unroll
    for (int j = 0; j < 8; ++j) {
        int k = s * 32 + ((l >> 4) * 8) + j;
        int n = t * 16 + (l & 15);
        int g = n >> 6, jj = n & 63;
        float v = W[(((size_t)r * 3 + (g == 0 ? 0 : g)) * Kin + k) * 64 + jj];
        if (g == 0) v -= W[(((size_t)r * 3 + 2) * Kin + k) * 64 + jj];
        short hi = f2b(v);
        short lo = f2b(v - b2f(hi));
        bh[(size_t)idx * 8 + j] = hi;
        bl[(size_t)idx * 8 + j] = lo;
    }
}

__global__ __launch_bounds__(256) void wpack64(const float* __restrict__ W,
                                               short* __restrict__ bh, short* __restrict__ bl) {
    int idx = blockIdx.x * 256 + threadIdx.x;
    if (idx >= 512) return;
    int l = idx & 63;
    int s = (idx >> 6) & 1;
    int t = idx >> 7;
#pragma unroll
    for (int j = 0; j < 8; ++j) {
        int k = s * 32 + ((l >> 4) * 8) + j;
        int n = t * 16 + (l & 15);
        float v = W[k * 64 + n];
        short hi = f2b(v);
        short lo = f2b(v - b2f(hi));
        bh[(size_t)idx * 8 + j] = hi;
        bl[(size_t)idx * 8 + j] = lo;
    }
}

// ---------------- device bodies ----------------

// edge scatter into CAP-sized dst/src bucket regions (256 threads)
__device__ void dev_scatter(int bid, const int* __restrict__ src, const int* __restrict__ dst,
                            int* __restrict__ bcurD, int* __restrict__ bcurS,
                            unsigned* __restrict__ pairs, unsigned char* __restrict__ srcs) {
    __shared__ int lcD[NBK], lbD[NBK], loD[NBK];
    __shared__ int lcS[NBK], lbS[NBK], loS[NBK];
    int t = threadIdx.x;
    for (int i = t; i < NBK; i += 256) { lcD[i] = 0; loD[i] = 0; lcS[i] = 0; loS[i] = 0; }
    __syncthreads();
    int base = bid * 8192;
#pragma unroll
    for (int i = 0; i < 32; ++i) {
        int e = base + i * 256 + t;
        if (e < EE) {
            atomicAdd(&lcD[dst[e] >> 8], 1);
            atomicAdd(&lcS[src[e] >> 8], 1);
        }
    }
    __syncthreads();
    for (int i = t; i < NBK; i += 256) {
        lbD[i] = lcD[i] ? atomicAdd(&bcurD[i], lcD[i]) : 0;
        lbS[i] = lcS[i] ? atomicAdd(&bcurS[i], lcS[i]) : 0;
    }
    __syncthreads();
#pragma unroll
    for (int i = 0; i < 32; ++i) {
        int e = base + i * 256 + t;
        if (e < EE) {
            int s = src[e], d = dst[e];
            int bD = d >> 8, bS = s >> 8;
            int pD = lbD[bD] + atomicAdd(&loD[bD], 1);
            if (pD >= 0 && pD < CAP)
                pairs[(size_t)bD * CAP + pD] = ((unsigned)s << 8) | (unsigned)(d & 255);
            int pS = lbS[bS] + atomicAdd(&loS[bS], 1);
            if (pS >= 0 && pS < CAP)
                srcs[(size_t)bS * CAP + pS] = (unsigned char)(s & 255);
        }
    }
}

// per-dst-bucket CSR: key = dstLocal*8 | srcSlice; hist -> scan -> rowp2 -> scatter (256 thr)
__device__ void dev_csr(int b, const unsigned* __restrict__ pairs,
                        const int* __restrict__ bcurD,
                        int* __restrict__ rowp2, int* __restrict__ csr) {
    __shared__ int hist[2048];
    __shared__ int wsums[4];
    int t = threadIdx.x;
    int p0 = b * CAP;
    int cnt = min(bcurD[b], CAP);
    int p1 = p0 + cnt;
    for (int i = t; i < 2048; i += 256) hist[i] = 0;
    __syncthreads();
    for (int e = p0 + t; e < p1; e += 256) {
        unsigned pr = pairs[e];
        int key = ((pr & 255) << 3) | (int)((pr >> 8) >> 14);
        atomicAdd(&hist[key], 1);
    }
    __syncthreads();
    int s[8];
    int run = 0;
#pragma unroll
    for (int i = 0; i < 8; ++i) { s[i] = run; run += hist[t * 8 + i]; }
    int lane = t & 63, wv = t >> 6;
    int x = run;
#pragma unroll
    for (int d = 1; d < 64; d <<= 1) {
        int y = __shfl_up(x, d, 64);
        if (lane >= d) x += y;
    }
    if (lane == 63) wsums[wv] = x;
    __syncthreads();
    int woff = 0;
    for (int wi = 0; wi < wv; ++wi) woff += wsums[wi];
    int excl = woff + x - run;
    rowp2[b * 257 + t] = p0 + excl;
    if (t == 0) rowp2[b * 257 + 256] = p1;
    __syncthreads();
#pragma unroll
    for (int i = 0; i < 8; ++i) hist[t * 8 + i] = p0 + excl + s[i];
    __syncthreads();
    for (int e = p0 + t; e < p1; e += 256) {
        unsigned pr = pairs[e];
        int key = ((pr & 255) << 3) | (int)((pr >> 8) >> 14);
        int pos = atomicAdd(&hist[key], 1);
        if (pos >= 0 && pos < NBK * CAP) csr[pos] = (int)(pr >> 8);
    }
}

// per-src-bucket degree -> dis (256 threads)
__device__ void dev_deg(int b, const unsigned char* __restrict__ srcs,
                        const int* __restrict__ bcurS, float* __restrict__ dis) {
    __shared__ int hist2[256];
    int t = threadIdx.x;
    hist2[t] = 0;
    __syncthreads();
    int cnt = min(bcurS[b], CAP);
    const unsigned char* sp = srcs + (size_t)b * CAP;
    for (int e = t; e < cnt; e += 256)
        atomicAdd(&hist2[sp[e]], 1);
    __syncthreads();
    int node = b * 256 + t;
    if (node < NN) {
        int d = hist2[t];
        dis[node] = d > 0 ? rsqrtf((float)d) : 0.f;
    }
}

// MFMA GEMM tile body (256 threads), LDS-staged C writes (16B coalesced).
// ntn multiple of 4; group g (4 tiles) -> output g: 0->o0, 1->o1, 2->o2.
// rowscale applied to tiles >= scale_from.
template <int KDIM>
__device__ void dev_gemm(int bid, const short* __restrict__ A, int lda,
                         const short* __restrict__ bph, const short* __restrict__ bplo,
                         int ntn,
                         short* __restrict__ o0, int ld0,
                         short* __restrict__ o1, int ld1,
                         short* __restrict__ o2, int ld2,
                         const float* __restrict__ bias, int scale_from,
                         const float* __restrict__ rowscale, int do_relu) {
    __shared__ short cstage[64][72];
    constexpr int KS = KDIM / 32;
    int tid = threadIdx.x;
    int w = tid >> 6, l = tid & 63;
    int rows0 = bid * 64;
    int arow = rows0 + w * 16 + (l & 15);
    int kbase = (l >> 4) * 8;
    bf16x8 af[KS];
#pragma unroll
    for (int s = 0; s < KS; ++s) {
        bf16x8 t = {0, 0, 0, 0, 0, 0, 0, 0};
        if (arow < NN) t = *(const bf16x8*)(A + (size_t)arow * lda + s * 32 + kbase);
        af[s] = t;
    }
    int ngroups = ntn >> 2;
    for (int gq = 0; gq < ngroups; ++gq) {
        float vres[4][4];
#pragma unroll
        for (int tt = 0; tt < 4; ++tt) {
            int t = gq * 4 + tt;
            f32x4 acc = {0.f, 0.f, 0.f, 0.f};
            const short* bp0 = bph + (((size_t)t * KS) * 64 + l) * 8;
            const short* bl0 = bplo + (((size_t)t * KS) * 64 + l) * 8;
#pragma unroll
            for (int s = 0; s < KS; ++s) {
                bf16x8 bh = *(const bf16x8*)(bp0 + (size_t)s * 64 * 8);
                bf16x8 bl = *(const bf16x8*)(bl0 + (size_t)s * 64 * 8);
                acc = __builtin_amdgcn_mfma_f32_16x16x32_bf16(af[s], bh, acc, 0, 0, 0);
                acc = __builtin_amdgcn_mfma_f32_16x16x32_bf16(af[s], bl, acc, 0, 0, 0);
            }
            int lcol = tt * 16 + (l & 15);
            bool scl = (rowscale != nullptr) && (t >= scale_from);
#pragma unroll
            for (int r_ = 0; r_ < 4; ++r_) {
                int row = rows0 + w * 16 + (l >> 4) * 4 + r_;
                float v = acc[r_];
                if (bias) v += bias[lcol];
                if (do_relu) v = fmaxf(v, 0.f);
                if (scl && row < NN) v *= rowscale[row];
                vres[tt][r_] = v;
            }
        }
        __syncthreads();   // cstage free from previous group
#pragma unroll
        for (int tt = 0; tt < 4; ++tt)
#pragma unroll
            for (int r_ = 0; r_ < 4; ++r_)
                cstage[w * 16 + (l >> 4) * 4 + r_][tt * 16 + (l & 15)] = f2b(vres[tt][r_]);
        __syncthreads();
        short* o = gq == 0 ? o0 : (gq == 1 ? o1 : o2);
        int ldc = gq == 0 ? ld0 : (gq == 1 ? ld1 : ld2);
        for (int p = tid; p < 512; p += 256) {
            int rl = p >> 3, q = p & 7;
            int grow = rows0 + rl;
            if (grow < NN)
                *(uint4*)(o + (size_t)grow * ldc + q * 8) = *(const uint4*)&cstage[rl][q * 8];
        }
    }
}

// ---------------- standalone wrappers (prologue) ----------------

__global__ __launch_bounds__(256) void scatter_k(const int* src, const int* dst,
                                                 int* bcurD, int* bcurS,
                                                 unsigned* pairs, unsigned char* srcs) {
    dev_scatter(blockIdx.x, src, dst, bcurD, bcurS, pairs, srcs);
}

__global__ __launch_bounds__(256) void csrdeg_k(const unsigned* pairs, const unsigned char* srcs,
                                                const int* bcurD, const int* bcurS,
                                                int* rowp2, int* csr, float* dis) {
    int b = blockIdx.x;
    if (b < NBK) dev_csr(b, pairs, bcurD, rowp2, csr);
    else dev_deg(b - NBK, srcs, bcurS, dis);
}

// ---------------- fused launches: extra blocks FIRST for co-residency ----------------

template <int KDIM>
__global__ __launch_bounds__(256) void gemm_scatter(int nextra,
                                                    const short* A, int lda,
                                                    const short* bph, const short* bplo,
                                                    int ntn,
                                                    short* o0, int ld0, short* o1, int ld1,
                                                    short* o2, int ld2,
                                                    const float* bias, int scale_from,
                                                    const float* rowscale, int do_relu,
                                                    const int* src, const int* dst,
                                                    int* bcurD, int* bcurS,
                                                    unsigned* pairs, unsigned char* srcs) {
    if ((int)blockIdx.x < nextra) {
        dev_scatter(blockIdx.x, src, dst, bcurD, bcurS, pairs, srcs);
    } else {
        dev_gemm<KDIM>(blockIdx.x - nextra, A, lda, bph, bplo, ntn,
                       o0, ld0, o1, ld1, o2, ld2, bias, scale_from, rowscale, do_relu);
    }
}

template <int KDIM>
__global__ __launch_bounds__(256) void gemm_csrdeg(int nextra,
                                                   const short* A, int lda,
                                                   const short* bph, const short* bplo,
                                                   int ntn,
                                                   short* o0, int ld0, short* o1, int ld1,
                                                   short* o2, int ld2,
                                                   const float* bias, int scale_from,
                                                   const float* rowscale, int do_relu,
                                                   const unsigned* pairs, const unsigned char* srcs,
                                                   const int* bcurD, const int* bcurS,
                                                   int* rowp2n, int* csrn, float* disn) {
    if ((int)blockIdx.x < nextra) {
        int b = blockIdx.x;
        if (b < NBK) dev_csr(b, pairs, bcurD, rowp2n, csrn);
        else dev_deg(b - NBK, srcs, bcurS, disn);
    } else {
        dev_gemm<KDIM>(blockIdx.x - nextra, A, lda, bph, bplo, ntn,
                       o0, ld0, o1, ld1, o2, ld2, bias, scale_from, rowscale, do_relu);
    }
}

// ---------------- SpMM: 8 lanes/row, 16B gathers, masked batches + idx prefetch ----------------
// MID=1: outb[row,:] = bf16( aux[row,:] - 2*dis^2 * sum v[src,:] )           (aux=y1)
// MID=0: outb[row,:] = bf16( relu(aux[row,:] + (-dis)*sum v[src,:] + bias) )  (aux=t0; may be in-place)
template <int MID>
__global__ __launch_bounds__(256) void spmm_bf(const short* __restrict__ v,
                                               const short* __restrict__ aux,
                                               short* __restrict__ outb, int ldc,
                                               const int* __restrict__ csr,
                                               const int* __restrict__ rowp2,
                                               const float* __restrict__ dis,
                                               const float* __restrict__ bias) {
    int t = threadIdx.x;
    int wv = t >> 6, l = t & 63;
    int g = l >> 3, fl = l & 7;
    int row = blockIdx.x * 32 + wv * 8 + g;
    if (row >= NN) return;
    int b = row >> 8, ri = row & 255;
    int s0 = rowp2[b * 257 + ri];
    int s1 = rowp2[b * 257 + ri + 1];
    s0 = max(s0, b * CAP);
    s1 = min(s1, b * CAP + CAP);
    float a[8] = {0.f, 0.f, 0.f, 0.f, 0.f, 0.f, 0.f, 0.f};
    if (s0 < s1) {
        int e = s0;
        int idx[8], nidx[8];
        int last = s1 - 1;
#pragma unroll
        for (int i = 0; i < 8; ++i) idx[i] = csr[min(e + i, last)];
        for (;;) {
            uint4 u[8];
#pragma unroll
            for (int i = 0; i < 8; ++i)
                u[i] = *(const uint4*)(v + (size_t)idx[i] * 64 + fl * 8);
            int en = e + 8;
            bool nhave = en < s1;
            if (nhave) {
#pragma unroll
                for (int i = 0; i < 8; ++i) nidx[i] = csr[min(en + i, last)];
            }
#pragma unroll
            for (int i = 0; i < 8; ++i) {
                float m = (e + i < s1) ? 1.f : 0.f;
                a[0] = fmaf(m, ulo(u[i].x), a[0]); a[1] = fmaf(m, uhi(u[i].x), a[1]);
                a[2] = fmaf(m, ulo(u[i].y), a[2]); a[3] = fmaf(m, uhi(u[i].y), a[3]);
                a[4] = fmaf(m, ulo(u[i].z), a[4]); a[5] = fmaf(m, uhi(u[i].z), a[5]);
                a[6] = fmaf(m, ulo(u[i].w), a[6]); a[7] = fmaf(m, uhi(u[i].w), a[7]);
            }
            if (!nhave) break;
#pragma unroll
            for (int i = 0; i < 8; ++i) idx[i] = nidx[i];
            e = en;
        }
    }
    float d = dis[row];
    uint4 au = *(const uint4*)(aux + (size_t)row * 64 + fl * 8);
    float av[8] = {ulo(au.x), uhi(au.x), ulo(au.y), uhi(au.y),
                   ulo(au.z), uhi(au.z), ulo(au.w), uhi(au.w)};
    float vv[8];
    if (MID) {
        float mm = -2.f * d * d;
#pragma unroll
        for (int i = 0; i < 8; ++i) vv[i] = av[i] + mm * a[i];
    } else {
        float4 bs0 = *(const float4*)(bias + fl * 8);
        float4 bs1 = *(const float4*)(bias + fl * 8 + 4);
        float bb[8] = {bs0.x, bs0.y, bs0.z, bs0.w, bs1.x, bs1.y, bs1.z, bs1.w};
#pragma unroll
        for (int i = 0; i < 8; ++i) vv[i] = fmaxf(av[i] - d * a[i] + bb[i], 0.f);
    }
    uint4 o;
    o.x = pck(vv[0], vv[1]); o.y = pck(vv[2], vv[3]);
    o.z = pck(vv[4], vv[5]); o.w = pck(vv[6], vv[7]);
    *(uint4*)(outb + (size_t)row * ldc + fl * 8) = o;
}

// ---------------- gate MLP + aux + softmax + fuse ----------------
__global__ __launch_bounds__(384) void gate_fuse(const short* __restrict__ stack,
                                                 const short* __restrict__ g1h,
                                                 const short* __restrict__ g1l,
                                                 const float* __restrict__ gb1,
                                                 const float* __restrict__ gw2,
                                                 const float* __restrict__ gb2,
                                                 const float* __restrict__ auxw,
                                                 const float* __restrict__ auxb,
                                                 short* __restrict__ hfused,
                                                 float* __restrict__ out) {
    __shared__ float glog[384];
    __shared__ float alpha[64][6];
    int t = threadIdx.x;
    int w = t / 64, l = t & 63;
    int nb = blockIdx.x * 64;
    int rowsw = nb * 6 + w * 64;
    int kbase = (l >> 4) * 8;
    bf16x8 af[4][2];
#pragma unroll
    for (int q = 0; q < 4; ++q) {
        int arow = rowsw + q * 16 + (l & 15);
        bool ok = arow < NN * RR;
#pragma unroll
        for (int s = 0; s < 2; ++s) {
            bf16x8 z = {0, 0, 0, 0, 0, 0, 0, 0};
            af[q][s] = ok ? *(const bf16x8*)(stack + (size_t)arow * 64 + s * 32 + kbase) : z;
        }
        int rmod = arow % RR;
        float paux = 0.f;
#pragma unroll
        for (int s = 0; s < 2; ++s) {
            const float* aw = auxw + rmod * 64 + s * 32 + kbase;
#pragma unroll
            for (int j = 0; j < 8; ++j) paux = fmaf(b2f(af[q][s][j]), aw[j], paux);
        }
        paux += __shfl_xor(paux, 16, 64);
        paux += __shfl_xor(paux, 32, 64);
        int orow = rowsw + q * 16 + l;
        if (l < 16 && orow < NN * RR) out[NN + (size_t)orow] = paux + auxb[orow % RR];
    }
    float pt[4][4];
#pragma unroll
    for (int q = 0; q < 4; ++q)
#pragma unroll
        for (int r_ = 0; r_ < 4; ++r_) pt[q][r_] = 0.f;
#pragma unroll
    for (int tc = 0; tc < 4; ++tc) {
        int col = tc * 16 + (l & 15);
        float bcol = gb1[col], w2 = gw2[col];
        bf16x8 bh0 = *(const bf16x8*)(g1h + (((size_t)tc * 2 + 0) * 64 + l) * 8);
        bf16x8 bl0 = *(const bf16x8*)(g1l + (((size_t)tc * 2 + 0) * 64 + l) * 8);
        bf16x8 bh1 = *(const bf16x8*)(g1h + (((size_t)tc * 2 + 1) * 64 + l) * 8);
        bf16x8 bl1 = *(const bf16x8*)(g1l + (((size_t)tc * 2 + 1) * 64 + l) * 8);
#pragma unroll
        for (int q = 0; q < 4; ++q) {
            f32x4 acc = {0.f, 0.f, 0.f, 0.f};
            acc = __builtin_amdgcn_mfma_f32_16x16x32_bf16(af[q][0], bh0, acc, 0, 0, 0);
            acc = __builtin_amdgcn_mfma_f32_16x16x32_bf16(af[q][0], bl0, acc, 0, 0, 0);
            acc = __builtin_amdgcn_mfma_f32_16x16x32_bf16(af[q][1], bh1, acc, 0, 0, 0);
            acc = __builtin_amdgcn_mfma_f32_16x16x32_bf16(af[q][1], bl1, acc, 0, 0, 0);
#pragma unroll
            for (int r_ = 0; r_ < 4; ++r_) {
                float h = fmaxf(acc[r_] + bcol, 0.f);
                pt[q][r_] = fmaf(h, w2, pt[q][r_]);
            }
        }
    }
#pragma unroll
    for (int q = 0; q < 4; ++q) {
#pragma unroll
        for (int d = 1; d < 16; d <<= 1)
#pragma unroll
            for (int r_ = 0; r_ < 4; ++r_) pt[q][r_] += __shfl_xor(pt[q][r_], d, 64);
        if ((l & 15) == 0) {
            float g2 = gb2[0];
#pragma unroll
            for (int r_ = 0; r_ < 4; ++r_)
                glog[w * 64 + q * 16 + (l >> 4) * 4 + r_] = pt[q][r_] + g2;
        }
    }
    __syncthreads();
    if (t < 64 && nb + t < NN) {
        float gl[RR];
        float m = -1e30f;
#pragma unroll
        for (int r = 0; r < RR; ++r) {
            gl[r] = glog[t * 6 + r];
            m = fmaxf(m, gl[r]);
        }
        float ssum = 0.f;
#pragma unroll
        for (int r = 0; r < RR; ++r) {
            gl[r] = __expf(gl[r] - m);
            ssum += gl[r];
        }
        float inv = 1.f / ssum;
#pragma unroll
        for (int r = 0; r < RR; ++r) alpha[t][r] = gl[r] * inv;
    }
    __syncthreads();
    for (int i = t; i < 2048; i += 384) {
        int nl = i >> 5, c2 = (i & 31) * 2;
        int n = nb + nl;
        if (n >= NN) break;
        float hf0 = 0.f, hf1 = 0.f;
#pragma unroll
        for (int r = 0; r < RR; ++r) {
            unsigned u = *(const unsigned*)(stack + ((size_t)n * RR + r) * 64 + c2);
            float al = alpha[nl][r];
            hf0 = fmaf(al, ulo(u), hf0);
            hf1 = fmaf(al, uhi(u), hf1);
        }
        *(unsigned*)(hfused + (size_t)n * 64 + c2) = pck(hf0, hf1);
    }
}

// ---------------- cls via MFMA ----------------
__global__ __launch_bounds__(256) void cls_mfma(const short* __restrict__ hproj,
                                                const short* __restrict__ c1h,
                                                const short* __restrict__ c1l,
                                                const float* __restrict__ cb1,
                                                const float* __restrict__ cw2,
                                                const float* __restrict__ cb2,
                                                float* __restrict__ out) {
    int w = threadIdx.x >> 6, l = threadIdx.x & 63;
    int rows0 = blockIdx.x * 64 + w * 16;
    int arow = rows0 + (l & 15);
    int kbase = (l >> 4) * 8;
    bf16x8 af[2];
#pragma unroll
    for (int s = 0; s < 2; ++s) {
        bf16x8 t = {0, 0, 0, 0, 0, 0, 0, 0};
        if (arow < NN) t = *(const bf16x8*)(hproj + (size_t)arow * 64 + s * 32 + kbase);
        af[s] = t;
    }
    float p[4] = {0.f, 0.f, 0.f, 0.f};
#pragma unroll
    for (int t = 0; t < 4; ++t) {
        f32x4 acc = {0.f, 0.f, 0.f, 0.f};
#pragma unroll
        for (int s = 0; s < 2; ++s) {
            bf16x8 bh = *(const bf16x8*)(c1h + (((size_t)t * 2 + s) * 64 + l) * 8);
            bf16x8 bl = *(const bf16x8*)(c1l + (((size_t)t * 2 + s) * 64 + l) * 8);
            acc = __builtin_amdgcn_mfma_f32_16x16x32_bf16(af[s], bh, acc, 0, 0, 0);
            acc = __builtin_amdgcn_mfma_f32_16x16x32_bf16(af[s], bl, acc, 0, 0, 0);
        }
        int col = t * 16 + (l & 15);
        float b = cb1[col], w2 = cw2[col];
#pragma unroll
        for (int r_ = 0; r_ < 4; ++r_) {
            float h = fmaxf(acc[r_] + b, 0.f);
            p[r_] = fmaf(h, w2, p[r_]);
        }
    }
#pragma unroll
    for (int d = 1; d < 16; d <<= 1) {
#pragma unroll
        for (int r_ = 0; r_ < 4; ++r_) p[r_] += __shfl_xor(p[r_], d, 64);
    }
    if ((l & 15) == 0) {
        float c2 = cb2[0];
#pragma unroll
        for (int r_ = 0; r_ < 4; ++r_) {
            int row = rows0 + (l >> 4) * 4 + r_;
            if (row < NN) out[row] = p[r_] + c2;
        }
    }
}

// ---------------- host ----------------

extern "C" void kernel_launch(void* const* d_in, const int* in_sizes, int n_in,
                              void* d_out, int out_size, void* d_ws, size_t ws_size,
                              hipStream_t stream) {
    const float* x = (const float*)d_in[0];
    const int* ei = (const int*)d_in[1];
    const float* c1w = (const float*)d_in[2];
    const float* c1b = (const float*)d_in[3];
    const float* c2w = (const float*)d_in[4];
    const float* c2b = (const float*)d_in[5];
    const float* gw1 = (const float*)d_in[6];
    const float* gb1 = (const float*)d_in[7];
    const float* gw2 = (const float*)d_in[8];
    const float* gb2 = (const float*)d_in[9];
    const float* pw = (const float*)d_in[10];
    const float* pb = (const float*)d_in[11];
    const float* cw1 = (const float*)d_in[12];
    const float* cb1 = (const float*)d_in[13];
    const float* cw2 = (const float*)d_in[14];
    const float* cb2 = (const float*)d_in[15];
    const float* auxw = (const float*)d_in[16];
    const float* auxb = (const float*)d_in[17];
    float* out = (float*)d_out;

    char* wsp = (char*)d_ws;
    size_t off = 0;
    auto carve = [&](size_t bytes) -> char* {
        char* p = wsp + off;
        off += (bytes + 255) & ~(size_t)255;
        return p;
    };
    short* stack = (short*)carve((size_t)NN * RR * 64 * 2);
    short* y1b = (short*)carve((size_t)NN * 64 * 2);
    short* y2b = (short*)carve((size_t)NN * 64 * 2);          // also hproj
    short* wb = (short*)carve((size_t)NN * 64 * 2);
    short* tb = (short*)carve((size_t)NN * 64 * 2);           // t0 / h1 (in-place) / hfused
    short* xb = (short*)carve((size_t)NN * 128 * 2);
    float* dis = (float*)carve((size_t)2 * NN * 4);           // double-buffered
    int* rowp2 = (int*)carve((size_t)2 * NBK * 257 * 4);      // double-buffered
    int* csr = (int*)carve((size_t)2 * NBK * CAP * 4);        // double-buffered
    unsigned* pairs = (unsigned*)carve((size_t)NBK * CAP * 4);
    unsigned char* srcs = (unsigned char*)carve((size_t)NBK * CAP);
    int* cnts = (int*)carve((size_t)2 * RR * NBK * 4);
    short* bp1h = (short*)carve((size_t)RR * 12 * 4 * 64 * 8 * 2);
    short* bp1l = (short*)carve((size_t)RR * 12 * 4 * 64 * 8 * 2);
    short* bp2h = (short*)carve((size_t)RR * 12 * 2 * 64 * 8 * 2);
    short* bp2l = (short*)carve((size_t)RR * 12 * 2 * 64 * 8 * 2);
    short* g1h = (short*)carve((size_t)512 * 8 * 2);
    short* g1l = (short*)carve((size_t)512 * 8 * 2);
    short* pwh = (short*)carve((size_t)512 * 8 * 2);
    short* pwl = (short*)carve((size_t)512 * 8 * 2);
    short* c1h = (short*)carve((size_t)512 * 8 * 2);
    short* c1l = (short*)carve((size_t)512 * 8 * 2);
    (void)in_sizes; (void)n_in; (void)out_size;

    if (off > ws_size) return;   // guard: clean absmax-fail => ws too small

    zero_cnts<<<(2 * RR * NBK + 255) / 256, 256, 0, stream>>>(cnts, 2 * RR * NBK);
    cvt_x<<<(NN * 128 / 8 + 255) / 256, 256, 0, stream>>>(x, xb);
    wpack_cheb<<<72, 256, 0, stream>>>(c1w, 128, 4, bp1h, bp1l);
    wpack_cheb<<<36, 256, 0, stream>>>(c2w, 64, 2, bp2h, bp2l);
    wpack64<<<2, 256, 0, stream>>>(gw1, g1h, g1l);
    wpack64<<<2, 256, 0, stream>>>(pw, pwh, pwl);
    wpack64<<<2, 256, 0, stream>>>(cw1, c1h, c1l);

    // prologue: build CSR for relation 0
    scatter_k<<<EB2, 256, 0, stream>>>(ei, ei + EE, cnts, cnts + NBK, pairs, srcs);
    csrdeg_k<<<2 * NBK, 256, 0, stream>>>(pairs, srcs, cnts, cnts + NBK,
                                          rowp2, csr, dis);

    for (int r = 0; r < RR; ++r) {
        int cur = r & 1, nxt = cur ^ 1;
        int valid = (r < RR - 1) ? 1 : 0;
        const short* b1h = bp1h + (size_t)r * 12 * 4 * 64 * 8;
        const short* b1l = bp1l + (size_t)r * 12 * 4 * 64 * 8;
        const short* b2h = bp2h + (size_t)r * 12 * 2 * 64 * 8;
        const short* b2l = bp2l + (size_t)r * 12 * 2 * 64 * 8;
        const int* srcN = ei + (size_t)(r + 1) * 2 * EE;
        const int* dstN = srcN + EE;
        int* bcurDN = cnts + (size_t)(2 * (r + 1) % (2 * RR)) * NBK;
        int* bcurSN = bcurDN + NBK;
        const int* csrC = csr + (size_t)cur * NBK * CAP;
        const int* rowp2C = rowp2 + (size_t)cur * NBK * 257;
        const float* disC = dis + (size_t)cur * NN;
        int* csrN = csr + (size_t)nxt * NBK * CAP;
        int* rowp2N = rowp2 + (size_t)nxt * NBK * 257;
        float* disN = dis + (size_t)nxt * NN;

        // layer 1 GEMM + (scatter for r+1)
        gemm_scatter<128><<<GB + (valid ? EB2 : 0), 256, 0, stream>>>(
            valid ? EB2 : 0, xb, 128, b1h, b1l, 12,
            tb, 64, y1b, 64, y2b, 64, nullptr, 4, disC, 0,
            srcN, dstN, bcurDN, bcurSN, pairs, srcs);
        spmm_bf<1><<<NN / 32, 256, 0, stream>>>(y2b, y1b, wb, 64, csrC, rowp2C, disC, nullptr);
        spmm_bf<0><<<NN / 32, 256, 0, stream>>>(wb, tb, tb, 64, csrC, rowp2C, disC,
                                                c1b + r * 64);   // h1 in-place in tb
        // layer 2 GEMM + (csr_build + deg_dis for r+1)
        gemm_csrdeg<64><<<GB + (valid ? 2 * NBK : 0), 256, 0, stream>>>(
            valid ? 2 * NBK : 0, tb, 64, b2h, b2l, 12,
            tb, 64, y1b, 64, y2b, 64, nullptr, 4, disC, 0,
            pairs, srcs, bcurDN, bcurSN, rowp2N, csrN, disN);
        spmm_bf<1><<<NN / 32, 256, 0, stream>>>(y2b, y1b, wb, 64, csrC, rowp2C, disC, nullptr);
        spmm_bf<0><<<NN / 32, 256, 0, stream>>>(wb, tb, stack + r * 64, RR * 64,
                                                csrC, rowp2C, disC, c2b + r * 64);
    }
    gate_fuse<<<GB, 384, 0, stream>>>(stack, g1h, g1l, gb1, gw2, gb2,
                                      auxw, auxb, tb, out);
    gemm_scatter<64><<<GB, 256, 0, stream>>>(0, tb, 64, pwh, pwl, 4,
                                             y2b, 64, nullptr, 0, nullptr, 0,
                                             pb, 99, nullptr, 1,
                                             nullptr, nullptr, nullptr, nullptr,
                                             nullptr, nullptr);
    cls_mfma<<<GB, 256, 0, stream>>>(y2b, c1h, c1l, cb1, cw2, cb2, out);
}

// Round 16
// 1375.413 us; speedup vs baseline: 1.2545x; 1.0210x over previous
//
#include <hip/hip_runtime.h>
#include <hip/hip_bf16.h>

#define NN 100000
#define EE 1600000
#define RR 6
#define NBK 391        // dst/src buckets of 256 nodes
#define EB2 196        // edge blocks (8192 edges each)
#define CAP 4608       // per-bucket edge capacity (mean 4096, +8 sigma)
#define GB 1563        // ceil(NN/64)
#define CVB 6250       // cvt_x blocks (NN*128/8/256)

typedef __attribute__((ext_vector_type(8))) short bf16x8;
typedef __attribute__((ext_vector_type(4))) float f32x4;

__device__ inline short f2b(float x) {
    __hip_bfloat16 h = __float2bfloat16(x);
    return *reinterpret_cast<short*>(&h);
}
__device__ inline float b2f(short s) {
    __hip_bfloat16 h = *reinterpret_cast<__hip_bfloat16*>(&s);
    return __bfloat162float(h);
}
__device__ inline float ulo(unsigned u) { return __uint_as_float(u << 16); }
__device__ inline float uhi(unsigned u) { return __uint_as_float(u & 0xffff0000u); }
__device__ inline unsigned pck(float a, float b) {
    return (unsigned)(unsigned short)f2b(a) | ((unsigned)(unsigned short)f2b(b) << 16);
}

// ---------------- small setup kernels ----------------

__global__ __launch_bounds__(256) void zero_cnts(int* p, int n) {
    int i = blockIdx.x * 256 + threadIdx.x;
    if (i < n) p[i] = 0;
}

__global__ __launch_bounds__(256) void wpack_cheb(const float* __restrict__ W, int Kin, int KS,
                                                  short* __restrict__ bh, short* __restrict__ bl) {
    int idx = blockIdx.x * 256 + threadIdx.x;
    int l = idx & 63;
    int q = idx >> 6;
    int s = q % KS; q /= KS;
    int t = q % 12; q /= 12;
    int r = q;
    if (r >= RR) return;
#pragma unroll
    for (int j = 0; j < 8; ++j) {
        int k = s * 32 + ((l >> 4) * 8) + j;
        int n = t * 16 + (l & 15);
        int g = n >> 6, jj = n & 63;
        float v = W[(((size_t)r * 3 + (g == 0 ? 0 : g)) * Kin + k) * 64 + jj];
        if (g == 0) v -= W[(((size_t)r * 3 + 2) * Kin + k) * 64 + jj];
        short hi = f2b(v);
        short lo = f2b(v - b2f(hi));
        bh[(size_t)idx * 8 + j] = hi;
        bl[(size_t)idx * 8 + j] = lo;
    }
}

__global__ __launch_bounds__(256) void wpack64(const float* __restrict__ W,
                                               short* __restrict__ bh, short* __restrict__ bl) {
    int idx = blockIdx.x * 256 + threadIdx.x;
    if (idx >= 512) return;
    int l = idx & 63;
    int s = (idx >> 6) & 1;
    int t = idx >> 7;
#pragma unroll
    for (int j = 0; j < 8; ++j) {
        int k = s * 32 + ((l >> 4) * 8) + j;
        int n = t * 16 + (l & 15);
        float v = W[k * 64 + n];
        short hi = f2b(v);
        short lo = f2b(v - b2f(hi));
        bh[(size_t)idx * 8 + j] = hi;
        bl[(size_t)idx * 8 + j] = lo;
    }
}

// ---------------- device bodies ----------------

// edge scatter into CAP-sized dst/src bucket regions (256 threads)
__device__ void dev_scatter(int bid, const int* __restrict__ src, const int* __restrict__ dst,
                            int* __restrict__ bcurD, int* __restrict__ bcurS,
                            unsigned* __restrict__ pairs, unsigned char* __restrict__ srcs) {
    __shared__ int lcD[NBK], lbD[NBK], loD[NBK];
    __shared__ int lcS[NBK], lbS[NBK], loS[NBK];
    int t = threadIdx.x;
    for (int i = t; i < NBK; i += 256) { lcD[i] = 0; loD[i] = 0; lcS[i] = 0; loS[i] = 0; }
    __syncthreads();
    int base = bid * 8192;
#pragma unroll
    for (int i = 0; i < 32; ++i) {
        int e = base + i * 256 + t;
        if (e < EE) {
            atomicAdd(&lcD[dst[e] >> 8], 1);
            atomicAdd(&lcS[src[e] >> 8], 1);
        }
    }
    __syncthreads();
    for (int i = t; i < NBK; i += 256) {
        lbD[i] = lcD[i] ? atomicAdd(&bcurD[i], lcD[i]) : 0;
        lbS[i] = lcS[i] ? atomicAdd(&bcurS[i], lcS[i]) : 0;
    }
    __syncthreads();
#pragma unroll
    for (int i = 0; i < 32; ++i) {
        int e = base + i * 256 + t;
        if (e < EE) {
            int s = src[e], d = dst[e];
            int bD = d >> 8, bS = s >> 8;
            int pD = lbD[bD] + atomicAdd(&loD[bD], 1);
            if (pD >= 0 && pD < CAP)
                pairs[(size_t)bD * CAP + pD] = ((unsigned)s << 8) | (unsigned)(d & 255);
            int pS = lbS[bS] + atomicAdd(&loS[bS], 1);
            if (pS >= 0 && pS < CAP)
                srcs[(size_t)bS * CAP + pS] = (unsigned char)(s & 255);
        }
    }
}

// per-dst-bucket CSR: key = dstLocal*8 | srcSlice; hist -> scan -> rowp2 -> scatter (256 thr)
__device__ void dev_csr(int b, const unsigned* __restrict__ pairs,
                        const int* __restrict__ bcurD,
                        int* __restrict__ rowp2, int* __restrict__ csr) {
    __shared__ int hist[2048];
    __shared__ int wsums[4];
    int t = threadIdx.x;
    int p0 = b * CAP;
    int cnt = min(bcurD[b], CAP);
    int p1 = p0 + cnt;
    for (int i = t; i < 2048; i += 256) hist[i] = 0;
    __syncthreads();
    for (int e = p0 + t; e < p1; e += 256) {
        unsigned pr = pairs[e];
        int key = ((pr & 255) << 3) | (int)((pr >> 8) >> 14);
        atomicAdd(&hist[key], 1);
    }
    __syncthreads();
    int s[8];
    int run = 0;
#pragma unroll
    for (int i = 0; i < 8; ++i) { s[i] = run; run += hist[t * 8 + i]; }
    int lane = t & 63, wv = t >> 6;
    int x = run;
#pragma unroll
    for (int d = 1; d < 64; d <<= 1) {
        int y = __shfl_up(x, d, 64);
        if (lane >= d) x += y;
    }
    if (lane == 63) wsums[wv] = x;
    __syncthreads();
    int woff = 0;
    for (int wi = 0; wi < wv; ++wi) woff += wsums[wi];
    int excl = woff + x - run;
    rowp2[b * 257 + t] = p0 + excl;
    if (t == 0) rowp2[b * 257 + 256] = p1;
    __syncthreads();
#pragma unroll
    for (int i = 0; i < 8; ++i) hist[t * 8 + i] = p0 + excl + s[i];
    __syncthreads();
    for (int e = p0 + t; e < p1; e += 256) {
        unsigned pr = pairs[e];
        int key = ((pr & 255) << 3) | (int)((pr >> 8) >> 14);
        int pos = atomicAdd(&hist[key], 1);
        if (pos >= 0 && pos < NBK * CAP) csr[pos] = (int)(pr >> 8);
    }
}

// per-src-bucket degree -> dis (256 threads)
__device__ void dev_deg(int b, const unsigned char* __restrict__ srcs,
                        const int* __restrict__ bcurS, float* __restrict__ dis) {
    __shared__ int hist2[256];
    int t = threadIdx.x;
    hist2[t] = 0;
    __syncthreads();
    int cnt = min(bcurS[b], CAP);
    const unsigned char* sp = srcs + (size_t)b * CAP;
    for (int e = t; e < cnt; e += 256)
        atomicAdd(&hist2[sp[e]], 1);
    __syncthreads();
    int node = b * 256 + t;
    if (node < NN) {
        int d = hist2[t];
        dis[node] = d > 0 ? rsqrtf((float)d) : 0.f;
    }
}

// MFMA GEMM tile body (256 threads), LDS-staged C writes (16B coalesced).
template <int KDIM>
__device__ void dev_gemm(int bid, const short* __restrict__ A, int lda,
                         const short* __restrict__ bph, const short* __restrict__ bplo,
                         int ntn,
                         short* __restrict__ o0, int ld0,
                         short* __restrict__ o1, int ld1,
                         short* __restrict__ o2, int ld2,
                         const float* __restrict__ bias, int scale_from,
                         const float* __restrict__ rowscale, int do_relu) {
    __shared__ short cstage[64][72];
    constexpr int KS = KDIM / 32;
    int tid = threadIdx.x;
    int w = tid >> 6, l = tid & 63;
    int rows0 = bid * 64;
    int arow = rows0 + w * 16 + (l & 15);
    int kbase = (l >> 4) * 8;
    bf16x8 af[KS];
#pragma unroll
    for (int s = 0; s < KS; ++s) {
        bf16x8 t = {0, 0, 0, 0, 0, 0, 0, 0};
        if (arow < NN) t = *(const bf16x8*)(A + (size_t)arow * lda + s * 32 + kbase);
        af[s] = t;
    }
    int ngroups = ntn >> 2;
    for (int gq = 0; gq < ngroups; ++gq) {
        float vres[4][4];
#pragma unroll
        for (int tt = 0; tt < 4; ++tt) {
            int t = gq * 4 + tt;
            f32x4 acc = {0.f, 0.f, 0.f, 0.f};
            const short* bp0 = bph + (((size_t)t * KS) * 64 + l) * 8;
            const short* bl0 = bplo + (((size_t)t * KS) * 64 + l) * 8;
#pragma unroll
            for (int s = 0; s < KS; ++s) {
                bf16x8 bh = *(const bf16x8*)(bp0 + (size_t)s * 64 * 8);
                bf16x8 bl = *(const bf16x8*)(bl0 + (size_t)s * 64 * 8);
                acc = __builtin_amdgcn_mfma_f32_16x16x32_bf16(af[s], bh, acc, 0, 0, 0);
                acc = __builtin_amdgcn_mfma_f32_16x16x32_bf16(af[s], bl, acc, 0, 0, 0);
            }
            int lcol = tt * 16 + (l & 15);
            bool scl = (rowscale != nullptr) && (t >= scale_from);
#pragma unroll
            for (int r_ = 0; r_ < 4; ++r_) {
                int row = rows0 + w * 16 + (l >> 4) * 4 + r_;
                float v = acc[r_];
                if (bias) v += bias[lcol];
                if (do_relu) v = fmaxf(v, 0.f);
                if (scl && row < NN) v *= rowscale[row];
                vres[tt][r_] = v;
            }
        }
        __syncthreads();
#pragma unroll
        for (int tt = 0; tt < 4; ++tt)
#pragma unroll
            for (int r_ = 0; r_ < 4; ++r_)
                cstage[w * 16 + (l >> 4) * 4 + r_][tt * 16 + (l & 15)] = f2b(vres[tt][r_]);
        __syncthreads();
        short* o = gq == 0 ? o0 : (gq == 1 ? o1 : o2);
        int ldc = gq == 0 ? ld0 : (gq == 1 ? ld1 : ld2);
        for (int p = tid; p < 512; p += 256) {
            int rl = p >> 3, q = p & 7;
            int grow = rows0 + rl;
            if (grow < NN)
                *(uint4*)(o + (size_t)grow * ldc + q * 8) = *(const uint4*)&cstage[rl][q * 8];
        }
    }
}

// ---------------- prologue: relation-0 scatter fused with cvt_x ----------------

__global__ __launch_bounds__(256) void cvt_scatter(const float* __restrict__ x,
                                                   short* __restrict__ xb,
                                                   const int* src, const int* dst,
                                                   int* bcurD, int* bcurS,
                                                   unsigned* pairs, unsigned char* srcs) {
    if ((int)blockIdx.x < EB2) {
        dev_scatter(blockIdx.x, src, dst, bcurD, bcurS, pairs, srcs);
    } else {
        int i = ((int)blockIdx.x - EB2) * 256 + threadIdx.x;
        if (i >= NN * 128 / 8) return;
        const float* p = x + (size_t)i * 8;
        float4 u0 = *(const float4*)p;
        float4 u1 = *(const float4*)(p + 4);
        bf16x8 t;
        t[0] = f2b(u0.x); t[1] = f2b(u0.y); t[2] = f2b(u0.z); t[3] = f2b(u0.w);
        t[4] = f2b(u1.x); t[5] = f2b(u1.y); t[6] = f2b(u1.z); t[7] = f2b(u1.w);
        *(bf16x8*)(xb + (size_t)i * 8) = t;
    }
}

__global__ __launch_bounds__(256) void csrdeg_k(const unsigned* pairs, const unsigned char* srcs,
                                                const int* bcurD, const int* bcurS,
                                                int* rowp2, int* csr, float* dis) {
    int b = blockIdx.x;
    if (b < NBK) dev_csr(b, pairs, bcurD, rowp2, csr);
    else dev_deg(b - NBK, srcs, bcurS, dis);
}

// ---------------- fused launches: extra blocks FIRST for co-residency ----------------

template <int KDIM>
__global__ __launch_bounds__(256) void gemm_scatter(int nextra,
                                                    const short* A, int lda,
                                                    const short* bph, const short* bplo,
                                                    int ntn,
                                                    short* o0, int ld0, short* o1, int ld1,
                                                    short* o2, int ld2,
                                                    const float* bias, int scale_from,
                                                    const float* rowscale, int do_relu,
                                                    const int* src, const int* dst,
                                                    int* bcurD, int* bcurS,
                                                    unsigned* pairs, unsigned char* srcs) {
    if ((int)blockIdx.x < nextra) {
        dev_scatter(blockIdx.x, src, dst, bcurD, bcurS, pairs, srcs);
    } else {
        dev_gemm<KDIM>(blockIdx.x - nextra, A, lda, bph, bplo, ntn,
                       o0, ld0, o1, ld1, o2, ld2, bias, scale_from, rowscale, do_relu);
    }
}

template <int KDIM>
__global__ __launch_bounds__(256) void gemm_csrdeg(int nextra,
                                                   const short* A, int lda,
                                                   const short* bph, const short* bplo,
                                                   int ntn,
                                                   short* o0, int ld0, short* o1, int ld1,
                                                   short* o2, int ld2,
                                                   const float* bias, int scale_from,
                                                   const float* rowscale, int do_relu,
                                                   const unsigned* pairs, const unsigned char* srcs,
                                                   const int* bcurD, const int* bcurS,
                                                   int* rowp2n, int* csrn, float* disn) {
    if ((int)blockIdx.x < nextra) {
        int b = blockIdx.x;
        if (b < NBK) dev_csr(b, pairs, bcurD, rowp2n, csrn);
        else dev_deg(b - NBK, srcs, bcurS, disn);
    } else {
        dev_gemm<KDIM>(blockIdx.x - nextra, A, lda, bph, bplo, ntn,
                       o0, ld0, o1, ld1, o2, ld2, bias, scale_from, rowscale, do_relu);
    }
}

// ---------------- SpMM: 8 lanes/row, 16B gathers, masked batches + idx prefetch ----------------
// MID=1: outb[row,:] = bf16( aux[row,:] - 2*dis^2 * sum v[src,:] )           (aux=y1)
// MID=0: outb[row,:] = bf16( relu(aux[row,:] + (-dis)*sum v[src,:] + bias) )  (aux=t0; may be in-place)
template <int MID>
__global__ __launch_bounds__(256) void spmm_bf(const short* __restrict__ v,
                                               const short* __restrict__ aux,
                                               short* __restrict__ outb, int ldc,
                                               const int* __restrict__ csr,
                                               const int* __restrict__ rowp2,
                                               const float* __restrict__ dis,
                                               const float* __restrict__ bias) {
    int t = threadIdx.x;
    int wv = t >> 6, l = t & 63;
    int g = l >> 3, fl = l & 7;
    int row = blockIdx.x * 32 + wv * 8 + g;
    if (row >= NN) return;
    int b = row >> 8, ri = row & 255;
    int s0 = rowp2[b * 257 + ri];
    int s1 = rowp2[b * 257 + ri + 1];
    s0 = max(s0, b * CAP);
    s1 = min(s1, b * CAP + CAP);
    float a[8] = {0.f, 0.f, 0.f, 0.f, 0.f, 0.f, 0.f, 0.f};
    if (s0 < s1) {
        int e = s0;
        int idx[8], nidx[8];
        int last = s1 - 1;
#pragma unroll
        for (int i = 0; i < 8; ++i) idx[i] = csr[min(e + i, last)];
        for (;;) {
            uint4 u[8];
#pragma unroll
            for (int i = 0; i < 8; ++i)
                u[i] = *(const uint4*)(v + (size_t)idx[i] * 64 + fl * 8);
            int en = e + 8;
            bool nhave = en < s1;
            if (nhave) {
#pragma unroll
                for (int i = 0; i < 8; ++i) nidx[i] = csr[min(en + i, last)];
            }
#pragma unroll
            for (int i = 0; i < 8; ++i) {
                float m = (e + i < s1) ? 1.f : 0.f;
                a[0] = fmaf(m, ulo(u[i].x), a[0]); a[1] = fmaf(m, uhi(u[i].x), a[1]);
                a[2] = fmaf(m, ulo(u[i].y), a[2]); a[3] = fmaf(m, uhi(u[i].y), a[3]);
                a[4] = fmaf(m, ulo(u[i].z), a[4]); a[5] = fmaf(m, uhi(u[i].z), a[5]);
                a[6] = fmaf(m, ulo(u[i].w), a[6]); a[7] = fmaf(m, uhi(u[i].w), a[7]);
            }
            if (!nhave) break;
#pragma unroll
            for (int i = 0; i < 8; ++i) idx[i] = nidx[i];
            e = en;
        }
    }
    float d = dis[row];
    uint4 au = *(const uint4*)(aux + (size_t)row * 64 + fl * 8);
    float av[8] = {ulo(au.x), uhi(au.x), ulo(au.y), uhi(au.y),
                   ulo(au.z), uhi(au.z), ulo(au.w), uhi(au.w)};
    float vv[8];
    if (MID) {
        float mm = -2.f * d * d;
#pragma unroll
        for (int i = 0; i < 8; ++i) vv[i] = av[i] + mm * a[i];
    } else {
        float4 bs0 = *(const float4*)(bias + fl * 8);
        float4 bs1 = *(const float4*)(bias + fl * 8 + 4);
        float bb[8] = {bs0.x, bs0.y, bs0.z, bs0.w, bs1.x, bs1.y, bs1.z, bs1.w};
#pragma unroll
        for (int i = 0; i < 8; ++i) vv[i] = fmaxf(av[i] - d * a[i] + bb[i], 0.f);
    }
    uint4 o;
    o.x = pck(vv[0], vv[1]); o.y = pck(vv[2], vv[3]);
    o.z = pck(vv[4], vv[5]); o.w = pck(vv[6], vv[7]);
    *(uint4*)(outb + (size_t)row * ldc + fl * 8) = o;
}

// ---------------- gate MLP + aux + softmax + fuse (192 threads, 32 nodes/block) ----------------
__global__ __launch_bounds__(192) void gate_fuse(const short* __restrict__ stack,
                                                 const short* __restrict__ g1h,
                                                 const short* __restrict__ g1l,
                                                 const float* __restrict__ gb1,
                                                 const float* __restrict__ gw2,
                                                 const float* __restrict__ gb2,
                                                 const float* __restrict__ auxw,
                                                 const float* __restrict__ auxb,
                                                 short* __restrict__ hfused,
                                                 float* __restrict__ out) {
    __shared__ float glog[192];
    __shared__ float alpha[32][6];
    int t = threadIdx.x;
    int w = t >> 6, l = t & 63;
    int nb = blockIdx.x * 32;
    int rowsw = nb * 6 + w * 64;
    int kbase = (l >> 4) * 8;
    bf16x8 af[4][2];
#pragma unroll
    for (int q = 0; q < 4; ++q) {
        int arow = rowsw + q * 16 + (l & 15);
        bool ok = arow < NN * RR;
#pragma unroll
        for (int s = 0; s < 2; ++s) {
            bf16x8 z = {0, 0, 0, 0, 0, 0, 0, 0};
            af[q][s] = ok ? *(const bf16x8*)(stack + (size_t)arow * 64 + s * 32 + kbase) : z;
        }
        int rmod = arow % RR;
        float paux = 0.f;
#pragma unroll
        for (int s = 0; s < 2; ++s) {
            const float* aw = auxw + rmod * 64 + s * 32 + kbase;
#pragma unroll
            for (int j = 0; j < 8; ++j) paux = fmaf(b2f(af[q][s][j]), aw[j], paux);
        }
        paux += __shfl_xor(paux, 16, 64);
        paux += __shfl_xor(paux, 32, 64);
        int orow = rowsw + q * 16 + l;
        if (l < 16 && orow < NN * RR) out[NN + (size_t)orow] = paux + auxb[orow % RR];
    }
    float pt[4][4];
#pragma unroll
    for (int q = 0; q < 4; ++q)
#pragma unroll
        for (int r_ = 0; r_ < 4; ++r_) pt[q][r_] = 0.f;
#pragma unroll
    for (int tc = 0; tc < 4; ++tc) {
        int col = tc * 16 + (l & 15);
        float bcol = gb1[col], w2 = gw2[col];
        bf16x8 bh0 = *(const bf16x8*)(g1h + (((size_t)tc * 2 + 0) * 64 + l) * 8);
        bf16x8 bl0 = *(const bf16x8*)(g1l + (((size_t)tc * 2 + 0) * 64 + l) * 8);
        bf16x8 bh1 = *(const bf16x8*)(g1h + (((size_t)tc * 2 + 1) * 64 + l) * 8);
        bf16x8 bl1 = *(const bf16x8*)(g1l + (((size_t)tc * 2 + 1) * 64 + l) * 8);
#pragma unroll
        for (int q = 0; q < 4; ++q) {
            f32x4 acc = {0.f, 0.f, 0.f, 0.f};
            acc = __builtin_amdgcn_mfma_f32_16x16x32_bf16(af[q][0], bh0, acc, 0, 0, 0);
            acc = __builtin_amdgcn_mfma_f32_16x16x32_bf16(af[q][0], bl0, acc, 0, 0, 0);
            acc = __builtin_amdgcn_mfma_f32_16x16x32_bf16(af[q][1], bh1, acc, 0, 0, 0);
            acc = __builtin_amdgcn_mfma_f32_16x16x32_bf16(af[q][1], bl1, acc, 0, 0, 0);
#pragma unroll
            for (int r_ = 0; r_ < 4; ++r_) {
                float h = fmaxf(acc[r_] + bcol, 0.f);
                pt[q][r_] = fmaf(h, w2, pt[q][r_]);
            }
        }
    }
#pragma unroll
    for (int q = 0; q < 4; ++q) {
#pragma unroll
        for (int d = 1; d < 16; d <<= 1)
#pragma unroll
            for (int r_ = 0; r_ < 4; ++r_) pt[q][r_] += __shfl_xor(pt[q][r_], d, 64);
        if ((l & 15) == 0) {
            float g2 = gb2[0];
#pragma unroll
            for (int r_ = 0; r_ < 4; ++r_)
                glog[w * 64 + q * 16 + (l >> 4) * 4 + r_] = pt[q][r_] + g2;
        }
    }
    __syncthreads();
    if (t < 32 && nb + t < NN) {
        float gl[RR];
        float m = -1e30f;
#pragma unroll
        for (int r = 0; r < RR; ++r) {
            gl[r] = glog[t * 6 + r];
            m = fmaxf(m, gl[r]);
        }
        float ssum = 0.f;
#pragma unroll
        for (int r = 0; r < RR; ++r) {
            gl[r] = __expf(gl[r] - m);
            ssum += gl[r];
        }
        float inv = 1.f / ssum;
#pragma unroll
        for (int r = 0; r < RR; ++r) alpha[t][r] = gl[r] * inv;
    }
    __syncthreads();
    for (int i = t; i < 1024; i += 192) {
        int nl = i >> 5, c2 = (i & 31) * 2;
        int n = nb + nl;
        if (n >= NN) break;
        float hf0 = 0.f, hf1 = 0.f;
#pragma unroll
        for (int r = 0; r < RR; ++r) {
            unsigned u = *(const unsigned*)(stack + ((size_t)n * RR + r) * 64 + c2);
            float al = alpha[nl][r];
            hf0 = fmaf(al, ulo(u), hf0);
            hf1 = fmaf(al, uhi(u), hf1);
        }
        *(unsigned*)(hfused + (size_t)n * 64 + c2) = pck(hf0, hf1);
    }
}

// ---------------- cls via MFMA ----------------
__global__ __launch_bounds__(256) void cls_mfma(const short* __restrict__ hproj,
                                                const short* __restrict__ c1h,
                                                const short* __restrict__ c1l,
                                                const float* __restrict__ cb1,
                                                const float* __restrict__ cw2,
                                                const float* __restrict__ cb2,
                                                float* __restrict__ out) {
    int w = threadIdx.x >> 6, l = threadIdx.x & 63;
    int rows0 = blockIdx.x * 64 + w * 16;
    int arow = rows0 + (l & 15);
    int kbase = (l >> 4) * 8;
    bf16x8 af[2];
#pragma unroll
    for (int s = 0; s < 2; ++s) {
        bf16x8 t = {0, 0, 0, 0, 0, 0, 0, 0};
        if (arow < NN) t = *(const bf16x8*)(hproj + (size_t)arow * 64 + s * 32 + kbase);
        af[s] = t;
    }
    float p[4] = {0.f, 0.f, 0.f, 0.f};
#pragma unroll
    for (int t = 0; t < 4; ++t) {
        f32x4 acc = {0.f, 0.f, 0.f, 0.f};
#pragma unroll
        for (int s = 0; s < 2; ++s) {
            bf16x8 bh = *(const bf16x8*)(c1h + (((size_t)t * 2 + s) * 64 + l) * 8);
            bf16x8 bl = *(const bf16x8*)(c1l + (((size_t)t * 2 + s) * 64 + l) * 8);
            acc = __builtin_amdgcn_mfma_f32_16x16x32_bf16(af[s], bh, acc, 0, 0, 0);
            acc = __builtin_amdgcn_mfma_f32_16x16x32_bf16(af[s], bl, acc, 0, 0, 0);
        }
        int col = t * 16 + (l & 15);
        float b = cb1[col], w2 = cw2[col];
#pragma unroll
        for (int r_ = 0; r_ < 4; ++r_) {
            float h = fmaxf(acc[r_] + b, 0.f);
            p[r_] = fmaf(h, w2, p[r_]);
        }
    }
#pragma unroll
    for (int d = 1; d < 16; d <<= 1) {
#pragma unroll
        for (int r_ = 0; r_ < 4; ++r_) p[r_] += __shfl_xor(p[r_], d, 64);
    }
    if ((l & 15) == 0) {
        float c2 = cb2[0];
#pragma unroll
        for (int r_ = 0; r_ < 4; ++r_) {
            int row = rows0 + (l >> 4) * 4 + r_;
            if (row < NN) out[row] = p[r_] + c2;
        }
    }
}

// ---------------- host ----------------

extern "C" void kernel_launch(void* const* d_in, const int* in_sizes, int n_in,
                              void* d_out, int out_size, void* d_ws, size_t ws_size,
                              hipStream_t stream) {
    const float* x = (const float*)d_in[0];
    const int* ei = (const int*)d_in[1];
    const float* c1w = (const float*)d_in[2];
    const float* c1b = (const float*)d_in[3];
    const float* c2w = (const float*)d_in[4];
    const float* c2b = (const float*)d_in[5];
    const float* gw1 = (const float*)d_in[6];
    const float* gb1 = (const float*)d_in[7];
    const float* gw2 = (const float*)d_in[8];
    const float* gb2 = (const float*)d_in[9];
    const float* pw = (const float*)d_in[10];
    const float* pb = (const float*)d_in[11];
    const float* cw1 = (const float*)d_in[12];
    const float* cb1 = (const float*)d_in[13];
    const float* cw2 = (const float*)d_in[14];
    const float* cb2 = (const float*)d_in[15];
    const float* auxw = (const float*)d_in[16];
    const float* auxb = (const float*)d_in[17];
    float* out = (float*)d_out;

    char* wsp = (char*)d_ws;
    size_t off = 0;
    auto carve = [&](size_t bytes) -> char* {
        char* p = wsp + off;
        off += (bytes + 255) & ~(size_t)255;
        return p;
    };
    short* stack = (short*)carve((size_t)NN * RR * 64 * 2);
    short* y1b = (short*)carve((size_t)NN * 64 * 2);
    short* y2b = (short*)carve((size_t)NN * 64 * 2);          // also hproj
    short* wb = (short*)carve((size_t)NN * 64 * 2);
    short* tb = (short*)carve((size_t)NN * 64 * 2);           // t0 / h1 (in-place) / hfused
    short* xb = (short*)carve((size_t)NN * 128 * 2);
    float* dis = (float*)carve((size_t)2 * NN * 4);           // double-buffered
    int* rowp2 = (int*)carve((size_t)2 * NBK * 257 * 4);      // double-buffered
    int* csr = (int*)carve((size_t)2 * NBK * CAP * 4);        // double-buffered
    unsigned* pairs = (unsigned*)carve((size_t)NBK * CAP * 4);
    unsigned char* srcs = (unsigned char*)carve((size_t)NBK * CAP);
    int* cnts = (int*)carve((size_t)2 * RR * NBK * 4);
    short* bp1h = (short*)carve((size_t)RR * 12 * 4 * 64 * 8 * 2);
    short* bp1l = (short*)carve((size_t)RR * 12 * 4 * 64 * 8 * 2);
    short* bp2h = (short*)carve((size_t)RR * 12 * 2 * 64 * 8 * 2);
    short* bp2l = (short*)carve((size_t)RR * 12 * 2 * 64 * 8 * 2);
    short* g1h = (short*)carve((size_t)512 * 8 * 2);
    short* g1l = (short*)carve((size_t)512 * 8 * 2);
    short* pwh = (short*)carve((size_t)512 * 8 * 2);
    short* pwl = (short*)carve((size_t)512 * 8 * 2);
    short* c1h = (short*)carve((size_t)512 * 8 * 2);
    short* c1l = (short*)carve((size_t)512 * 8 * 2);
    (void)in_sizes; (void)n_in; (void)out_size;

    if (off > ws_size) return;   // guard: clean absmax-fail => ws too small

    zero_cnts<<<(2 * RR * NBK + 255) / 256, 256, 0, stream>>>(cnts, 2 * RR * NBK);
    // relation-0 scatter rides the cvt_x launch (scatter blocks first)
    cvt_scatter<<<EB2 + CVB, 256, 0, stream>>>(x, xb, ei, ei + EE,
                                               cnts, cnts + NBK, pairs, srcs);
    wpack_cheb<<<72, 256, 0, stream>>>(c1w, 128, 4, bp1h, bp1l);
    wpack_cheb<<<36, 256, 0, stream>>>(c2w, 64, 2, bp2h, bp2l);
    wpack64<<<2, 256, 0, stream>>>(gw1, g1h, g1l);
    wpack64<<<2, 256, 0, stream>>>(pw, pwh, pwl);
    wpack64<<<2, 256, 0, stream>>>(cw1, c1h, c1l);
    csrdeg_k<<<2 * NBK, 256, 0, stream>>>(pairs, srcs, cnts, cnts + NBK,
                                          rowp2, csr, dis);

    for (int r = 0; r < RR; ++r) {
        int cur = r & 1, nxt = cur ^ 1;
        int valid = (r < RR - 1) ? 1 : 0;
        const short* b1h = bp1h + (size_t)r * 12 * 4 * 64 * 8;
        const short* b1l = bp1l + (size_t)r * 12 * 4 * 64 * 8;
        const short* b2h = bp2h + (size_t)r * 12 * 2 * 64 * 8;
        const short* b2l = bp2l + (size_t)r * 12 * 2 * 64 * 8;
        const int* srcN = ei + (size_t)(r + 1) * 2 * EE;
        const int* dstN = srcN + EE;
        int* bcurDN = cnts + (size_t)(2 * (r + 1) % (2 * RR)) * NBK;
        int* bcurSN = bcurDN + NBK;
        const int* csrC = csr + (size_t)cur * NBK * CAP;
        const int* rowp2C = rowp2 + (size_t)cur * NBK * 257;
        const float* disC = dis + (size_t)cur * NN;
        int* csrN = csr + (size_t)nxt * NBK * CAP;
        int* rowp2N = rowp2 + (size_t)nxt * NBK * 257;
        float* disN = dis + (size_t)nxt * NN;

        // layer 1 GEMM + (scatter for r+1)
        gemm_scatter<128><<<GB + (valid ? EB2 : 0), 256, 0, stream>>>(
            valid ? EB2 : 0, xb, 128, b1h, b1l, 12,
            tb, 64, y1b, 64, y2b, 64, nullptr, 4, disC, 0,
            srcN, dstN, bcurDN, bcurSN, pairs, srcs);
        spmm_bf<1><<<NN / 32, 256, 0, stream>>>(y2b, y1b, wb, 64, csrC, rowp2C, disC, nullptr);
        spmm_bf<0><<<NN / 32, 256, 0, stream>>>(wb, tb, tb, 64, csrC, rowp2C, disC,
                                                c1b + r * 64);   // h1 in-place in tb
        // layer 2 GEMM + (csr_build + deg_dis for r+1)
        gemm_csrdeg<64><<<GB + (valid ? 2 * NBK : 0), 256, 0, stream>>>(
            valid ? 2 * NBK : 0, tb, 64, b2h, b2l, 12,
            tb, 64, y1b, 64, y2b, 64, nullptr, 4, disC, 0,
            pairs, srcs, bcurDN, bcurSN, rowp2N, csrN, disN);
        spmm_bf<1><<<NN / 32, 256, 0, stream>>>(y2b, y1b, wb, 64, csrC, rowp2C, disC, nullptr);
        spmm_bf<0><<<NN / 32, 256, 0, stream>>>(wb, tb, stack + r * 64, RR * 64,
                                                csrC, rowp2C, disC, c2b + r * 64);
    }
    gate_fuse<<<(NN + 31) / 32, 192, 0, stream>>>(stack, g1h, g1l, gb1, gw2, gb2,
                                                  auxw, auxb, tb, out);
    gemm_scatter<64><<<GB, 256, 0, stream>>>(0, tb, 64, pwh, pwl, 4,
                                             y2b, 64, nullptr, 0, nullptr, 0,
                                             pb, 99, nullptr, 1,
                                             nullptr, nullptr, nullptr, nullptr,
                                             nullptr, nullptr);
    cls_mfma<<<GB, 256, 0, stream>>>(y2b, c1h, c1l, cb1, cw2, cb2, out);
}